// Round 1
// baseline (1704.831 us; speedup 1.0000x reference)
//
#include <hip/hip_runtime.h>

// ---------------------------------------------------------------------------
// InputMapCTRNN: T=256, B=128, I=64, C=256, H=512, O=128, ALPHA=1, EPS=1e-5
//
// h[t,b,n] = relu( sum_c ctx[t,b,c]*S_c + S_bias ),
//   S_c[m,n] = sum_i x[m,i]*WbT[n, c*64+i]  -> one MFMA GEMM M=32768,N=512,
//   K=16448. Scale folded into A: ahat[m, c*64+i] = bf16(ctx[m,c]*x[m,i])
//   built per-fragment in registers (scale is a per-lane scalar) -> pure
//   MFMA accumulation chain, LDS double-buffered glds staging of B.
// Recurrence: K=320 batched MFMA  ctx' = relu([Wcc|Wic] @ [ctx;x] + bias),
//   fused in one grid with the prep blocks (prep hides under recurrence).
//
// R1: k_big was LDS-read-BW bound (256KB ds_read per block-iter = 2048-3084
//   cyc vs 1242 matrix cyc -> MfmaUtil 42%). Wave tile 16m -> 32m (mt=2):
//   each B fragment feeds 2 MFMAs, halving LDS bytes/FLOP. Block tile
//   256m x 128n, grid 512. scale8 repack via v_cvt_pk_bf16_f32 (1 inst vs 4)
//   to keep the doubled scaling work off the VALU critical path.
// ---------------------------------------------------------------------------

typedef unsigned int  uint_t;
typedef unsigned short ushort_t;
typedef __attribute__((ext_vector_type(8))) short  short8;
typedef __attribute__((ext_vector_type(4))) short  short4v;
typedef __attribute__((ext_vector_type(4))) float  floatx4;

__device__ __forceinline__ ushort_t f2bf(float f) {
    uint_t u = __float_as_uint(f);
    u = (u + 0x7fffu + ((u >> 16) & 1u)) >> 16;   // RNE
    return (ushort_t)u;
}
__device__ __forceinline__ uint_t pack2(float a, float b) {
    return (uint_t)f2bf(a) | ((uint_t)f2bf(b) << 16);
}
__device__ __forceinline__ float blo(uint_t u) { return __uint_as_float(u << 16); }
__device__ __forceinline__ float bhi(uint_t u) { return __uint_as_float(u & 0xffff0000u); }

__device__ __forceinline__ void glds16(const void* g, void* l) {
    __builtin_amdgcn_global_load_lds(
        (const __attribute__((address_space(1))) unsigned int*)g,
        (__attribute__((address_space(3))) unsigned int*)l, 16, 0, 0);
}

// scale 8 packed bf16 by fp32 scalar, repack via v_cvt_pk_bf16_f32 (RNE)
__device__ __forceinline__ short8 scale8(short8 a, float s) {
    union { short8 v; uint_t u[4]; } in, out;
    in.v = a;
#pragma unroll
    for (int q = 0; q < 4; ++q) {
        float lo = blo(in.u[q]) * s;
        float hi = bhi(in.u[q]) * s;
        uint_t r;
        asm("v_cvt_pk_bf16_f32 %0, %1, %2" : "=v"(r) : "v"(lo), "v"(hi));
        out.u[q] = r;
    }
    return out.v;
}

// ---------------------------------------------------------------------------
// FUSED: blocks 0..7 = sequential ctx recurrence (K=320 MFMA, 1 barrier/step,
// LDS double-buffer, x read fp32 from input). blocks 8..1051 = prep (WbT
// transpose+cvt, Whh/Who/x -> bf16) — independent, hides under recurrence.
// ---------------------------------------------------------------------------
__global__ __launch_bounds__(256, 1) void k_fused(
        const float* __restrict__ x, const float* __restrict__ Wcc,
        const float* __restrict__ bcc, const float* __restrict__ Wic,
        const float* __restrict__ bic, const float* __restrict__ Wmap,
        const float* __restrict__ bmap, const float* __restrict__ Whh,
        const float* __restrict__ Who,
        ushort_t* WbT, ushort_t* Whhb, ushort_t* Whob, ushort_t* xbf,
        float* __restrict__ CTXT, float* __restrict__ ctx_out) {
    __shared__ __align__(16) char smem[32896];   // union: prep 32896 B / rec 20480 B
    const int tid = threadIdx.x;
    const int bid = blockIdx.x;

    if (bid >= 8) {
        const int pb = bid - 8;
        if (pb < 512) {                      // WbT[n][c*64+i] = Wmap[n*64+i][c]
            float* tl = (float*)smem;        // 32*257 floats
            const int n = pb;
            for (int p = 0; p < 2; ++p) {
                if (p) __syncthreads();
#pragma unroll
                for (int k = 0; k < 32; ++k)
                    tl[k * 257 + tid] = Wmap[(size_t)(n * 64 + p * 32 + k) * 256 + tid];
                __syncthreads();
#pragma unroll
                for (int k2 = 0; k2 < 32; ++k2) {
                    int o = k2 * 256 + tid;
                    int il = o & 31, c = o >> 5;
                    WbT[(size_t)n * 16448 + c * 64 + p * 32 + il] = f2bf(tl[il * 257 + c]);
                }
            }
            if (tid < 64) WbT[(size_t)n * 16448 + 16384 + tid] = f2bf(bmap[n * 64 + tid]);
        } else if (pb < 528) {
            size_t base = (size_t)(pb - 512) * 16384;
#pragma unroll
            for (int k = 0; k < 64; ++k) { size_t i = base + k * 256 + tid; Whhb[i] = f2bf(Whh[i]); }
        } else if (pb < 532) {
            size_t base = (size_t)(pb - 528) * 16384;
#pragma unroll
            for (int k = 0; k < 64; ++k) { size_t i = base + k * 256 + tid; Whob[i] = f2bf(Who[i]); }
        } else {
            size_t base = (size_t)(pb - 532) * 4096;
#pragma unroll
            for (int k = 0; k < 16; ++k) { size_t i = base + k * 256 + tid; xbf[i] = f2bf(x[i]); }
        }
        return;
    }

    // ---------------- recurrence: block g owns samples [g*16, g*16+16) ------
    char* bufs = smem;                          // 2 x 10240 B
    const int g = bid;
    const int lane = tid & 63, w = tid >> 6;
    const int l15 = lane & 15, quad = lane >> 4;
    const int bq = tid >> 4, o4 = tid & 15;     // x-staging role

    // A-fragments: Wcc (kb 0..7) + Wic (kb 8..9); row j = w*64+mt*16+l15
    short8 wf[4][8], wi[4][2];
#pragma unroll
    for (int mt = 0; mt < 4; ++mt) {
        const int j = w * 64 + mt * 16 + l15;
#pragma unroll
        for (int kb = 0; kb < 8; ++kb) {
            const float* src = Wcc + (size_t)j * 256 + kb * 32 + quad * 8;
            float4 a = *(const float4*)src;
            float4 b = *(const float4*)(src + 4);
            short8 s;
            s[0] = (short)f2bf(a.x); s[1] = (short)f2bf(a.y);
            s[2] = (short)f2bf(a.z); s[3] = (short)f2bf(a.w);
            s[4] = (short)f2bf(b.x); s[5] = (short)f2bf(b.y);
            s[6] = (short)f2bf(b.z); s[7] = (short)f2bf(b.w);
            wf[mt][kb] = s;
        }
#pragma unroll
        for (int kb = 0; kb < 2; ++kb) {
            const float* src = Wic + (size_t)j * 64 + kb * 32 + quad * 8;
            float4 a = *(const float4*)src;
            float4 b = *(const float4*)(src + 4);
            short8 s;
            s[0] = (short)f2bf(a.x); s[1] = (short)f2bf(a.y);
            s[2] = (short)f2bf(a.z); s[3] = (short)f2bf(a.w);
            s[4] = (short)f2bf(b.x); s[5] = (short)f2bf(b.y);
            s[6] = (short)f2bf(b.z); s[7] = (short)f2bf(b.w);
            wi[mt][kb] = s;
        }
    }
    float4 bias[4];
#pragma unroll
    for (int mt = 0; mt < 4; ++mt) {
        const int j0 = w * 64 + mt * 16 + quad * 4;
        float4 b1 = *(const float4*)(bic + j0);
        float4 b2 = *(const float4*)(bcc + j0);
        bias[mt] = (float4){b1.x + b2.x, b1.y + b2.y, b1.z + b2.z, b1.w + b2.w};
    }
    // init buf0: ctx=0 (granule rows 0..31), x_0 (rows 32..39)
    *(uint4*)(bufs + tid * 16) = (uint4){0, 0, 0, 0};
    *(uint4*)(bufs + (tid + 256) * 16) = (uint4){0, 0, 0, 0};
    {
        float4 xv = *(const float4*)(x + (size_t)(g * 16 + bq) * 64 + o4 * 4);
        short4v s4;
        s4[0] = (short)f2bf(xv.x); s4[1] = (short)f2bf(xv.y);
        s4[2] = (short)f2bf(xv.z); s4[3] = (short)f2bf(xv.w);
        *(short4v*)(bufs + (32 + (o4 >> 1)) * 256 + bq * 16 + (o4 & 1) * 8) = s4;
    }
    float4 y[4];
#pragma unroll
    for (int mt = 0; mt < 4; ++mt) y[mt] = (float4){0.f, 0.f, 0.f, 0.f};
    __syncthreads();

    int p = 0;
#pragma unroll 1
    for (int t = 0; t < 256; ++t) {
        char* bp = bufs + p * 10240;
        char* bn = bufs + (p ^ 1) * 10240;
        // CTXT[c][t*128 + b] = ctx entering step t (= y)
#pragma unroll
        for (int mt = 0; mt < 4; ++mt) {
            const int j0 = w * 64 + mt * 16 + quad * 4;
#pragma unroll
            for (int r = 0; r < 4; ++r)
                CTXT[(size_t)(j0 + r) * 32768 + t * 128 + g * 16 + l15] = (&y[mt].x)[r];
        }
        float4 xv;
        if (t < 255)
            xv = *(const float4*)(x + (size_t)((t + 1) * 128 + g * 16 + bq) * 64 + o4 * 4);
        floatx4 acc[4];
#pragma unroll
        for (int mt = 0; mt < 4; ++mt) acc[mt] = (floatx4){0.f, 0.f, 0.f, 0.f};
#pragma unroll
        for (int kb = 0; kb < 8; ++kb) {
            short8 bf = *(const short8*)(bp + (kb * 4 + quad) * 256 + l15 * 16);
#pragma unroll
            for (int mt = 0; mt < 4; ++mt)
                acc[mt] = __builtin_amdgcn_mfma_f32_16x16x32_bf16(wf[mt][kb], bf, acc[mt], 0, 0, 0);
        }
#pragma unroll
        for (int kb = 0; kb < 2; ++kb) {
            short8 bf = *(const short8*)(bp + ((8 + kb) * 4 + quad) * 256 + l15 * 16);
#pragma unroll
            for (int mt = 0; mt < 4; ++mt)
                acc[mt] = __builtin_amdgcn_mfma_f32_16x16x32_bf16(wi[mt][kb], bf, acc[mt], 0, 0, 0);
        }
#pragma unroll
        for (int mt = 0; mt < 4; ++mt) {
            y[mt].x = fmaxf(acc[mt][0] + bias[mt].x, 0.f);
            y[mt].y = fmaxf(acc[mt][1] + bias[mt].y, 0.f);
            y[mt].z = fmaxf(acc[mt][2] + bias[mt].z, 0.f);
            y[mt].w = fmaxf(acc[mt][3] + bias[mt].w, 0.f);
        }
        if (t < 255) {
#pragma unroll
            for (int mt = 0; mt < 4; ++mt) {
                const int c0 = w * 64 + mt * 16 + quad * 4;
                short4v s4;
                s4[0] = (short)f2bf(y[mt].x); s4[1] = (short)f2bf(y[mt].y);
                s4[2] = (short)f2bf(y[mt].z); s4[3] = (short)f2bf(y[mt].w);
                *(short4v*)(bn + (c0 >> 3) * 256 + l15 * 16 + (c0 & 7) * 2) = s4;
            }
            short4v s4;
            s4[0] = (short)f2bf(xv.x); s4[1] = (short)f2bf(xv.y);
            s4[2] = (short)f2bf(xv.z); s4[3] = (short)f2bf(xv.w);
            *(short4v*)(bn + (32 + (o4 >> 1)) * 256 + bq * 16 + (o4 & 1) * 8) = s4;
        }
        __syncthreads();
        p ^= 1;
    }
#pragma unroll
    for (int mt = 0; mt < 4; ++mt) {
        const int j0 = w * 64 + mt * 16 + quad * 4;
#pragma unroll
        for (int r = 0; r < 4; ++r)
            ctx_out[(size_t)(g * 16 + l15) * 256 + j0 + r] = (&y[mt].x)[r];
    }
}

// ---------------------------------------------------------------------------
// BIG GEMM: M=32768,N=512,K=16448, scale folded into A-fragments.
// 512 thr / 8 waves, block tile 256x128 (mt=2: wave tile 32m x 128n, each
// LDS B-fragment feeds 2 MFMAs -> halves LDS-read bytes/FLOP, which was the
// binding pipe at grid 1024 / 16m wave tile).
// BK=128, LDS DOUBLE-buffer (2x32 KB), glds(16B) for tile kk+1 issued right
// after the single per-iter barrier -> latency hidden behind compute.
// 1D grid 512, XCD swizzle: by = gidx&3.
// ---------------------------------------------------------------------------
__global__ __launch_bounds__(512, 4) void k_big(const ushort_t* __restrict__ xbf,
                                                const ushort_t* __restrict__ WbT,
                                                const float* __restrict__ CTXT,
                                                ushort_t* __restrict__ hbf) {
    __shared__ __align__(16) ushort_t Bt[2 * 128 * 128];   // 64 KB
    const int tid = threadIdx.x;
    const int lane = tid & 63, w = tid >> 6;               // 8 waves
    const int l15 = lane & 15, quad = lane >> 4;
    const int gidx = blockIdx.x;
    const int by = gidx & 3;                               // xcd = gidx&7
    const int bx = (gidx >> 3) * 2 + ((gidx >> 2) & 1);    // 0..127
    const int m0 = bx * 256, n0 = by * 128;
    const int mr0 = m0 + w * 32 + l15;                     // mt=0 A-row
    const int mr1 = mr0 + 16;                              // mt=1 A-row

    short8 afr[2][2];                                      // [mt][ks]: x row frag
    afr[0][0] = *(const short8*)(xbf + (size_t)mr0 * 64 + quad * 8);
    afr[0][1] = *(const short8*)(xbf + (size_t)mr0 * 64 + 32 + quad * 8);
    afr[1][0] = *(const short8*)(xbf + (size_t)mr1 * 64 + quad * 8);
    afr[1][1] = *(const short8*)(xbf + (size_t)mr1 * 64 + 32 + quad * 8);

    floatx4 acc[2][8];
#pragma unroll
    for (int mt = 0; mt < 2; ++mt)
#pragma unroll
        for (int nt = 0; nt < 8; ++nt) acc[mt][nt] = (floatx4){0.f, 0.f, 0.f, 0.f};

    // staging: granule G = w*256 + q*64 + lane; nr=G>>4; k8=(G&15)^(nr&15)
    const ushort_t* gq[4];
    ushort_t* lq[4];
#pragma unroll
    for (int q = 0; q < 4; ++q) {
        const int G = w * 256 + q * 64 + lane;
        const int nr = G >> 4;
        const int k8 = (G & 15) ^ (nr & 15);
        gq[q] = WbT + (size_t)(n0 + nr) * 16448 + k8 * 8;
        lq[q] = Bt + w * 2048 + q * 512;                   // wave-uniform base
    }
#pragma unroll
    for (int q = 0; q < 4; ++q) glds16(gq[q], lq[q]);      // tile 0 -> buf 0

    float scv[2][2];                                       // [h][mt]
    scv[0][0] = CTXT[mr0];           scv[0][1] = CTXT[mr1];
    scv[1][0] = CTXT[32768 + mr0];   scv[1][1] = CTXT[32768 + mr1];

    for (int kk = 0; kk < 129; ++kk) {
        const int p = kk & 1;
        __syncthreads();                                   // tile kk resident
        if (kk < 128) {                                    // prefetch tile kk+1
            const size_t koff = (size_t)(kk + 1) * 128;
            const int np = (p ^ 1) * 16384;
#pragma unroll
            for (int q = 0; q < 4; ++q) glds16(gq[q] + koff, lq[q] + np);
        }
        float scn[2][2] = {{1.f, 1.f}, {1.f, 1.f}};
        if (kk + 1 < 128) {
            scn[0][0] = CTXT[(size_t)(2 * kk + 2) * 32768 + mr0];
            scn[0][1] = CTXT[(size_t)(2 * kk + 2) * 32768 + mr1];
            scn[1][0] = CTXT[(size_t)(2 * kk + 3) * 32768 + mr0];
            scn[1][1] = CTXT[(size_t)(2 * kk + 3) * 32768 + mr1];
        }
        const ushort_t* bb = Bt + p * 16384;
        if (kk < 128) {
#pragma unroll
            for (int h = 0; h < 2; ++h) {
#pragma unroll
                for (int ks = 0; ks < 2; ++ks) {
                    short8 a0 = scale8(afr[0][ks], scv[h][0]);
                    short8 a1 = scale8(afr[1][ks], scv[h][1]);
#pragma unroll
                    for (int nt = 0; nt < 8; ++nt) {
                        const int nr = nt * 16 + l15;
                        const char* bpr = (const char*)bb + nr * 256;
                        short8 b = *(const short8*)(bpr + (((h * 8 + ks * 4 + quad) ^ l15) * 16));
                        acc[0][nt] = __builtin_amdgcn_mfma_f32_16x16x32_bf16(a0, b, acc[0][nt], 0, 0, 0);
                        acc[1][nt] = __builtin_amdgcn_mfma_f32_16x16x32_bf16(a1, b, acc[1][nt], 0, 0, 0);
                    }
                }
            }
        } else {                                           // bias block, scale=1
#pragma unroll
            for (int nt = 0; nt < 8; ++nt) {
                const int nr = nt * 16 + l15;
                const char* bpr = (const char*)bb + nr * 256;
                short8 b0 = *(const short8*)(bpr + ((quad ^ l15) * 16));
                short8 b1 = *(const short8*)(bpr + (((4 + quad) ^ l15) * 16));
                acc[0][nt] = __builtin_amdgcn_mfma_f32_16x16x32_bf16(afr[0][0], b0, acc[0][nt], 0, 0, 0);
                acc[0][nt] = __builtin_amdgcn_mfma_f32_16x16x32_bf16(afr[0][1], b1, acc[0][nt], 0, 0, 0);
                acc[1][nt] = __builtin_amdgcn_mfma_f32_16x16x32_bf16(afr[1][0], b0, acc[1][nt], 0, 0, 0);
                acc[1][nt] = __builtin_amdgcn_mfma_f32_16x16x32_bf16(afr[1][1], b1, acc[1][nt], 0, 0, 0);
            }
        }
        scv[0][0] = scn[0][0]; scv[0][1] = scn[0][1];
        scv[1][0] = scn[1][0]; scv[1][1] = scn[1][1];
    }
    // epilogue: C/D col = n0+nt*16+l15, row = m0 + w*32 + mt*16 + quad*4 + r
#pragma unroll
    for (int mt = 0; mt < 2; ++mt)
#pragma unroll
        for (int nt = 0; nt < 8; ++nt) {
            const int col = n0 + nt * 16 + l15;
#pragma unroll
            for (int r = 0; r < 4; ++r) {
                const int row = m0 + w * 32 + mt * 16 + quad * 4 + r;
                hbf[(size_t)row * 512 + col] = f2bf(fmaxf(acc[mt][nt][r], 0.f));
            }
        }
}

// ---------------------------------------------------------------------------
// Generic bf16 NT GEMM: C[m,n] = sum_k A[m,k]*B[n,k] + bias[n]
// ---------------------------------------------------------------------------
template <bool OUTF32>
__global__ __launch_bounds__(256, 2) void k_gemm_nt(const ushort_t* __restrict__ A,
                                                    const ushort_t* __restrict__ Bm,
                                                    const float* __restrict__ bias,
                                                    ushort_t* __restrict__ outb,
                                                    float* __restrict__ outf,
                                                    int K, int Nst) {
    __shared__ __align__(16) ushort_t At[128 * 72];
    __shared__ __align__(16) ushort_t Bt[128 * 72];
    const int tid = threadIdx.x;
    const int lane = tid & 63, w = tid >> 6;
    const int wm = w & 1, wn = w >> 1;
    const int l15 = lane & 15, quad = lane >> 4;
    const int m0 = blockIdx.x * 128, n0 = blockIdx.y * 128;

    const int r_l = tid >> 1, kh = (tid & 1) * 32;
    const ushort_t* gA = A + (size_t)(m0 + r_l) * K + kh;
    const ushort_t* gB = Bm + (size_t)(n0 + r_l) * K + kh;
    ushort_t* lA = &At[r_l * 72 + kh];
    ushort_t* lB = &Bt[r_l * 72 + kh];

    uint4 ra0 = *(const uint4*)(gA + 0), ra1 = *(const uint4*)(gA + 8);
    uint4 ra2 = *(const uint4*)(gA + 16), ra3 = *(const uint4*)(gA + 24);
    uint4 rb0 = *(const uint4*)(gB + 0), rb1 = *(const uint4*)(gB + 8);
    uint4 rb2 = *(const uint4*)(gB + 16), rb3 = *(const uint4*)(gB + 24);

    floatx4 acc[4][4];
#pragma unroll
    for (int i = 0; i < 4; ++i)
#pragma unroll
        for (int j = 0; j < 4; ++j) acc[i][j] = (floatx4){0.f, 0.f, 0.f, 0.f};

    const int niter = K >> 6;
    for (int kb = 0; kb < niter; ++kb) {
        __syncthreads();
        *(uint4*)(lA + 0) = ra0;  *(uint4*)(lA + 8) = ra1;
        *(uint4*)(lA + 16) = ra2; *(uint4*)(lA + 24) = ra3;
        *(uint4*)(lB + 0) = rb0;  *(uint4*)(lB + 8) = rb1;
        *(uint4*)(lB + 16) = rb2; *(uint4*)(lB + 24) = rb3;
        __syncthreads();
        if (kb + 1 < niter) {
            const ushort_t* ga = gA + (size_t)(kb + 1) * 64;
            const ushort_t* gb = gB + (size_t)(kb + 1) * 64;
            ra0 = *(const uint4*)(ga + 0);  ra1 = *(const uint4*)(ga + 8);
            ra2 = *(const uint4*)(ga + 16); ra3 = *(const uint4*)(ga + 24);
            rb0 = *(const uint4*)(gb + 0);  rb1 = *(const uint4*)(gb + 8);
            rb2 = *(const uint4*)(gb + 16); rb3 = *(const uint4*)(gb + 24);
        }
        short8 av[4][2];
#pragma unroll
        for (int mt = 0; mt < 4; ++mt) {
            const int mr = wm * 64 + mt * 16 + l15;
            av[mt][0] = *(const short8*)(&At[mr * 72 + quad * 8]);
            av[mt][1] = *(const short8*)(&At[mr * 72 + 32 + quad * 8]);
        }
#pragma unroll
        for (int nt = 0; nt < 4; ++nt) {
            const int nr = wn * 64 + nt * 16 + l15;
            short8 b0 = *(const short8*)(&Bt[nr * 72 + quad * 8]);
            short8 b1 = *(const short8*)(&Bt[nr * 72 + 32 + quad * 8]);
#pragma unroll
            for (int mt = 0; mt < 4; ++mt) {
                acc[mt][nt] = __builtin_amdgcn_mfma_f32_16x16x32_bf16(av[mt][0], b0, acc[mt][nt], 0, 0, 0);
                acc[mt][nt] = __builtin_amdgcn_mfma_f32_16x16x32_bf16(av[mt][1], b1, acc[mt][nt], 0, 0, 0);
            }
        }
    }
#pragma unroll
    for (int mt = 0; mt < 4; ++mt)
#pragma unroll
        for (int nt = 0; nt < 4; ++nt) {
            const int col = n0 + wn * 64 + nt * 16 + l15;
            const float bb = bias[col];
#pragma unroll
            for (int r = 0; r < 4; ++r) {
                const int row = m0 + wm * 64 + mt * 16 + quad * 4 + r;
                const float v = acc[mt][nt][r] + bb;
                if (OUTF32) outf[(size_t)row * Nst + col] = v;
                else        outb[(size_t)row * Nst + col] = f2bf(v);
            }
        }
}

// ---------------------------------------------------------------------------
// LayerNorm + residual: z = h + relu( LN(hn)*g + b ), in-place over hbf.
// ---------------------------------------------------------------------------
__global__ __launch_bounds__(256, 1) void k_ln(const ushort_t* __restrict__ hn,
                                               ushort_t* __restrict__ h,
                                               const float* __restrict__ g,
                                               const float* __restrict__ bb) {
    const int tid = threadIdx.x;
    const int lane = tid & 63;
    const int row = blockIdx.x * 4 + (tid >> 6);
    const uint4 hv = *(const uint4*)(hn + (size_t)row * 512 + lane * 8);
    float f[8];
    f[0] = blo(hv.x); f[1] = bhi(hv.x); f[2] = blo(hv.y); f[3] = bhi(hv.y);
    f[4] = blo(hv.z); f[5] = bhi(hv.z); f[6] = blo(hv.w); f[7] = bhi(hv.w);
    float s = 0.f, s2 = 0.f;
#pragma unroll
    for (int j = 0; j < 8; ++j) { s += f[j]; s2 = fmaf(f[j], f[j], s2); }
#pragma unroll
    for (int o = 32; o >= 1; o >>= 1) { s += __shfl_xor(s, o, 64); s2 += __shfl_xor(s2, o, 64); }
    const float mu = s * (1.f / 512.f);
    const float var = s2 * (1.f / 512.f) - mu * mu;
    const float rs = rsqrtf(var + 1e-5f);
    const uint4 hh = *(const uint4*)(h + (size_t)row * 512 + lane * 8);
    float hf[8];
    hf[0] = blo(hh.x); hf[1] = bhi(hh.x); hf[2] = blo(hh.y); hf[3] = bhi(hh.y);
    hf[4] = blo(hh.z); hf[5] = bhi(hh.z); hf[6] = blo(hh.w); hf[7] = bhi(hh.w);
    float4 g0 = *(const float4*)(g + lane * 8);  float4 g1 = *(const float4*)(g + lane * 8 + 4);
    float4 b0 = *(const float4*)(bb + lane * 8); float4 b1 = *(const float4*)(bb + lane * 8 + 4);
    const float gv[8] = {g0.x, g0.y, g0.z, g0.w, g1.x, g1.y, g1.z, g1.w};
    const float bv[8] = {b0.x, b0.y, b0.z, b0.w, b1.x, b1.y, b1.z, b1.w};
    float z[8];
#pragma unroll
    for (int j = 0; j < 8; ++j)
        z[j] = hf[j] + fmaxf((f[j] - mu) * rs * gv[j] + bv[j], 0.f);
    uint4 o;
    o.x = pack2(z[0], z[1]); o.y = pack2(z[2], z[3]);
    o.z = pack2(z[4], z[5]); o.w = pack2(z[6], z[7]);
    *(uint4*)(h + (size_t)row * 512 + lane * 8) = o;
}

// ---------------------------------------------------------------------------
extern "C" void kernel_launch(void* const* d_in, const int* in_sizes, int n_in,
                              void* d_out, int out_size, void* d_ws, size_t ws_size,
                              hipStream_t stream) {
    const float* x    = (const float*)d_in[0];
    const float* Wcc  = (const float*)d_in[1];
    const float* bcc  = (const float*)d_in[2];
    const float* Wic  = (const float*)d_in[3];
    const float* bic  = (const float*)d_in[4];
    const float* Wmap = (const float*)d_in[5];
    const float* bmap = (const float*)d_in[6];
    const float* Whh  = (const float*)d_in[7];
    const float* bhh  = (const float*)d_in[8];
    const float* ln_g = (const float*)d_in[9];
    const float* ln_b = (const float*)d_in[10];
    const float* Who  = (const float*)d_in[11];
    const float* bho  = (const float*)d_in[12];
    float* out = (float*)d_out;

    char* wsb = (char*)d_ws;
    ushort_t* WbT  = (ushort_t*)(wsb);                    // 16,842,752 B + 1 KB pad
    ushort_t* Whhb = (ushort_t*)(wsb + 16843776);         //    524,288
    ushort_t* Whob = (ushort_t*)(wsb + 17368064);         //    131,072
    ushort_t* xbf  = (ushort_t*)(wsb + 17499136);         //  4,194,304
    float*    CTXT = (float*)   (wsb + 21693440);         // 33,554,432
    ushort_t* hbf  = (ushort_t*)(wsb + 55247872);         // 33,554,432 (h, then z)
    ushort_t* hnbf = (ushort_t*)(wsb + 88802304);         // 33,554,432 -> ~122 MB

    k_fused<<<1052, 256, 0, stream>>>(x, Wcc, bcc, Wic, bic, Wmap, bmap, Whh, Who,
                                      WbT, Whhb, Whob, xbf, CTXT, out + 4194304);
    k_big<<<512, 512, 0, stream>>>(xbf, WbT, CTXT, hbf);
    k_gemm_nt<false><<<dim3(256, 4), 256, 0, stream>>>(hbf, Whhb, bhh, hnbf, nullptr, 512, 512);
    k_ln<<<8192, 256, 0, stream>>>(hnbf, hbf, ln_g, ln_b);
    k_gemm_nt<true><<<dim3(256, 1), 256, 0, stream>>>(hbf, Whob, bho, nullptr, out, 512, 128);
}

// Round 3
// 848.357 us; speedup vs baseline: 2.0096x; 2.0096x over previous
//
#include <hip/hip_runtime.h>

// ---------------------------------------------------------------------------
// InputMapCTRNN: T=256, B=128, I=64, C=256, H=512, O=128, ALPHA=1, EPS=1e-5
//
// h[t,b,n] = relu( sum_c ctx[t,b,c]*S_c + S_bias ),
//   S_c[m,n] = sum_i x[m,i]*WbT[n, c*64+i]  -> one MFMA GEMM M=32768,N=512,
//   K=16448. Scale folded into A: ahat[m, c*64+i] = bf16(ctx[m,c]*x[m,i])
//   built per-fragment in registers (scale is a per-lane scalar) -> pure
//   MFMA accumulation chain, LDS double-buffered glds staging of B.
// Recurrence: K=320 batched MFMA  ctx' = relu([Wcc|Wic] @ [ctx;x] + bias),
//   fused in one grid with the prep blocks (prep hides under recurrence).
//
// R1 (FAILED): mt=2 at 512thr/__launch_bounds__(512,4) capped VGPR at 128 ->
//   accumulator spill (WRITE_SIZE 32MB->1.27GB of scratch). Lesson: mt=2
//   needs ~150 VGPR.
// R2 (infra failure, never ran) / R3 (resubmit): mt=2 at 256thr/4 waves,
//   block tile 128x128, grid 1024 (same XCD swizzle), __launch_bounds__(256,2):
//   2 blocks/CU via LDS, VGPR cap 256 -> no spill. Each LDS B-fragment feeds
//   2 MFMAs (halves LDS-read bytes/FLOP, which bound R0 at MfmaUtil 42%).
// ---------------------------------------------------------------------------

typedef unsigned int  uint_t;
typedef unsigned short ushort_t;
typedef __attribute__((ext_vector_type(8))) short  short8;
typedef __attribute__((ext_vector_type(4))) short  short4v;
typedef __attribute__((ext_vector_type(4))) float  floatx4;

__device__ __forceinline__ ushort_t f2bf(float f) {
    uint_t u = __float_as_uint(f);
    u = (u + 0x7fffu + ((u >> 16) & 1u)) >> 16;   // RNE
    return (ushort_t)u;
}
__device__ __forceinline__ uint_t pack2(float a, float b) {
    return (uint_t)f2bf(a) | ((uint_t)f2bf(b) << 16);
}
__device__ __forceinline__ float blo(uint_t u) { return __uint_as_float(u << 16); }
__device__ __forceinline__ float bhi(uint_t u) { return __uint_as_float(u & 0xffff0000u); }

__device__ __forceinline__ void glds16(const void* g, void* l) {
    __builtin_amdgcn_global_load_lds(
        (const __attribute__((address_space(1))) unsigned int*)g,
        (__attribute__((address_space(3))) unsigned int*)l, 16, 0, 0);
}

// scale 8 packed bf16 by fp32 scalar, repack via v_cvt_pk_bf16_f32 (RNE)
__device__ __forceinline__ short8 scale8(short8 a, float s) {
    union { short8 v; uint_t u[4]; } in, out;
    in.v = a;
#pragma unroll
    for (int q = 0; q < 4; ++q) {
        float lo = blo(in.u[q]) * s;
        float hi = bhi(in.u[q]) * s;
        uint_t r;
        asm("v_cvt_pk_bf16_f32 %0, %1, %2" : "=v"(r) : "v"(lo), "v"(hi));
        out.u[q] = r;
    }
    return out.v;
}

// ---------------------------------------------------------------------------
// FUSED: blocks 0..7 = sequential ctx recurrence (K=320 MFMA, 1 barrier/step,
// LDS double-buffer, x read fp32 from input). blocks 8..1051 = prep (WbT
// transpose+cvt, Whh/Who/x -> bf16) — independent, hides under recurrence.
// ---------------------------------------------------------------------------
__global__ __launch_bounds__(256, 1) void k_fused(
        const float* __restrict__ x, const float* __restrict__ Wcc,
        const float* __restrict__ bcc, const float* __restrict__ Wic,
        const float* __restrict__ bic, const float* __restrict__ Wmap,
        const float* __restrict__ bmap, const float* __restrict__ Whh,
        const float* __restrict__ Who,
        ushort_t* WbT, ushort_t* Whhb, ushort_t* Whob, ushort_t* xbf,
        float* __restrict__ CTXT, float* __restrict__ ctx_out) {
    __shared__ __align__(16) char smem[32896];   // union: prep 32896 B / rec 20480 B
    const int tid = threadIdx.x;
    const int bid = blockIdx.x;

    if (bid >= 8) {
        const int pb = bid - 8;
        if (pb < 512) {                      // WbT[n][c*64+i] = Wmap[n*64+i][c]
            float* tl = (float*)smem;        // 32*257 floats
            const int n = pb;
            for (int p = 0; p < 2; ++p) {
                if (p) __syncthreads();
#pragma unroll
                for (int k = 0; k < 32; ++k)
                    tl[k * 257 + tid] = Wmap[(size_t)(n * 64 + p * 32 + k) * 256 + tid];
                __syncthreads();
#pragma unroll
                for (int k2 = 0; k2 < 32; ++k2) {
                    int o = k2 * 256 + tid;
                    int il = o & 31, c = o >> 5;
                    WbT[(size_t)n * 16448 + c * 64 + p * 32 + il] = f2bf(tl[il * 257 + c]);
                }
            }
            if (tid < 64) WbT[(size_t)n * 16448 + 16384 + tid] = f2bf(bmap[n * 64 + tid]);
        } else if (pb < 528) {
            size_t base = (size_t)(pb - 512) * 16384;
#pragma unroll
            for (int k = 0; k < 64; ++k) { size_t i = base + k * 256 + tid; Whhb[i] = f2bf(Whh[i]); }
        } else if (pb < 532) {
            size_t base = (size_t)(pb - 528) * 16384;
#pragma unroll
            for (int k = 0; k < 64; ++k) { size_t i = base + k * 256 + tid; Whob[i] = f2bf(Who[i]); }
        } else {
            size_t base = (size_t)(pb - 532) * 4096;
#pragma unroll
            for (int k = 0; k < 16; ++k) { size_t i = base + k * 256 + tid; xbf[i] = f2bf(x[i]); }
        }
        return;
    }

    // ---------------- recurrence: block g owns samples [g*16, g*16+16) ------
    char* bufs = smem;                          // 2 x 10240 B
    const int g = bid;
    const int lane = tid & 63, w = tid >> 6;
    const int l15 = lane & 15, quad = lane >> 4;
    const int bq = tid >> 4, o4 = tid & 15;     // x-staging role

    // A-fragments: Wcc (kb 0..7) + Wic (kb 8..9); row j = w*64+mt*16+l15
    short8 wf[4][8], wi[4][2];
#pragma unroll
    for (int mt = 0; mt < 4; ++mt) {
        const int j = w * 64 + mt * 16 + l15;
#pragma unroll
        for (int kb = 0; kb < 8; ++kb) {
            const float* src = Wcc + (size_t)j * 256 + kb * 32 + quad * 8;
            float4 a = *(const float4*)src;
            float4 b = *(const float4*)(src + 4);
            short8 s;
            s[0] = (short)f2bf(a.x); s[1] = (short)f2bf(a.y);
            s[2] = (short)f2bf(a.z); s[3] = (short)f2bf(a.w);
            s[4] = (short)f2bf(b.x); s[5] = (short)f2bf(b.y);
            s[6] = (short)f2bf(b.z); s[7] = (short)f2bf(b.w);
            wf[mt][kb] = s;
        }
#pragma unroll
        for (int kb = 0; kb < 2; ++kb) {
            const float* src = Wic + (size_t)j * 64 + kb * 32 + quad * 8;
            float4 a = *(const float4*)src;
            float4 b = *(const float4*)(src + 4);
            short8 s;
            s[0] = (short)f2bf(a.x); s[1] = (short)f2bf(a.y);
            s[2] = (short)f2bf(a.z); s[3] = (short)f2bf(a.w);
            s[4] = (short)f2bf(b.x); s[5] = (short)f2bf(b.y);
            s[6] = (short)f2bf(b.z); s[7] = (short)f2bf(b.w);
            wi[mt][kb] = s;
        }
    }
    float4 bias[4];
#pragma unroll
    for (int mt = 0; mt < 4; ++mt) {
        const int j0 = w * 64 + mt * 16 + quad * 4;
        float4 b1 = *(const float4*)(bic + j0);
        float4 b2 = *(const float4*)(bcc + j0);
        bias[mt] = (float4){b1.x + b2.x, b1.y + b2.y, b1.z + b2.z, b1.w + b2.w};
    }
    // init buf0: ctx=0 (granule rows 0..31), x_0 (rows 32..39)
    *(uint4*)(bufs + tid * 16) = (uint4){0, 0, 0, 0};
    *(uint4*)(bufs + (tid + 256) * 16) = (uint4){0, 0, 0, 0};
    {
        float4 xv = *(const float4*)(x + (size_t)(g * 16 + bq) * 64 + o4 * 4);
        short4v s4;
        s4[0] = (short)f2bf(xv.x); s4[1] = (short)f2bf(xv.y);
        s4[2] = (short)f2bf(xv.z); s4[3] = (short)f2bf(xv.w);
        *(short4v*)(bufs + (32 + (o4 >> 1)) * 256 + bq * 16 + (o4 & 1) * 8) = s4;
    }
    float4 y[4];
#pragma unroll
    for (int mt = 0; mt < 4; ++mt) y[mt] = (float4){0.f, 0.f, 0.f, 0.f};
    __syncthreads();

    int p = 0;
#pragma unroll 1
    for (int t = 0; t < 256; ++t) {
        char* bp = bufs + p * 10240;
        char* bn = bufs + (p ^ 1) * 10240;
        // CTXT[c][t*128 + b] = ctx entering step t (= y)
#pragma unroll
        for (int mt = 0; mt < 4; ++mt) {
            const int j0 = w * 64 + mt * 16 + quad * 4;
#pragma unroll
            for (int r = 0; r < 4; ++r)
                CTXT[(size_t)(j0 + r) * 32768 + t * 128 + g * 16 + l15] = (&y[mt].x)[r];
        }
        float4 xv;
        if (t < 255)
            xv = *(const float4*)(x + (size_t)((t + 1) * 128 + g * 16 + bq) * 64 + o4 * 4);
        floatx4 acc[4];
#pragma unroll
        for (int mt = 0; mt < 4; ++mt) acc[mt] = (floatx4){0.f, 0.f, 0.f, 0.f};
#pragma unroll
        for (int kb = 0; kb < 8; ++kb) {
            short8 bf = *(const short8*)(bp + (kb * 4 + quad) * 256 + l15 * 16);
#pragma unroll
            for (int mt = 0; mt < 4; ++mt)
                acc[mt] = __builtin_amdgcn_mfma_f32_16x16x32_bf16(wf[mt][kb], bf, acc[mt], 0, 0, 0);
        }
#pragma unroll
        for (int kb = 0; kb < 2; ++kb) {
            short8 bf = *(const short8*)(bp + ((8 + kb) * 4 + quad) * 256 + l15 * 16);
#pragma unroll
            for (int mt = 0; mt < 4; ++mt)
                acc[mt] = __builtin_amdgcn_mfma_f32_16x16x32_bf16(wi[mt][kb], bf, acc[mt], 0, 0, 0);
        }
#pragma unroll
        for (int mt = 0; mt < 4; ++mt) {
            y[mt].x = fmaxf(acc[mt][0] + bias[mt].x, 0.f);
            y[mt].y = fmaxf(acc[mt][1] + bias[mt].y, 0.f);
            y[mt].z = fmaxf(acc[mt][2] + bias[mt].z, 0.f);
            y[mt].w = fmaxf(acc[mt][3] + bias[mt].w, 0.f);
        }
        if (t < 255) {
#pragma unroll
            for (int mt = 0; mt < 4; ++mt) {
                const int c0 = w * 64 + mt * 16 + quad * 4;
                short4v s4;
                s4[0] = (short)f2bf(y[mt].x); s4[1] = (short)f2bf(y[mt].y);
                s4[2] = (short)f2bf(y[mt].z); s4[3] = (short)f2bf(y[mt].w);
                *(short4v*)(bn + (c0 >> 3) * 256 + l15 * 16 + (c0 & 7) * 2) = s4;
            }
            short4v s4;
            s4[0] = (short)f2bf(xv.x); s4[1] = (short)f2bf(xv.y);
            s4[2] = (short)f2bf(xv.z); s4[3] = (short)f2bf(xv.w);
            *(short4v*)(bn + (32 + (o4 >> 1)) * 256 + bq * 16 + (o4 & 1) * 8) = s4;
        }
        __syncthreads();
        p ^= 1;
    }
#pragma unroll
    for (int mt = 0; mt < 4; ++mt) {
        const int j0 = w * 64 + mt * 16 + quad * 4;
#pragma unroll
        for (int r = 0; r < 4; ++r)
            ctx_out[(size_t)(g * 16 + l15) * 256 + j0 + r] = (&y[mt].x)[r];
    }
}

// ---------------------------------------------------------------------------
// BIG GEMM: M=32768,N=512,K=16448, scale folded into A-fragments.
// 256 thr / 4 waves, block tile 128x128, wave tile 32m x 128n (mt=2: each
// LDS B-fragment feeds 2 MFMAs -> halves LDS-read bytes/FLOP vs R0).
// BK=128, LDS DOUBLE-buffer (2x32 KB), glds(16B) for tile kk+1 issued right
// after the single per-iter barrier -> latency hidden behind compute.
// 1D grid 1024, XCD swizzle: by = gidx&3 (one WbT n-slice per XCD L2).
// __launch_bounds__(256,2): 2 blocks/CU (LDS-limited), VGPR cap 256 ->
// ~150 live regs fit WITHOUT spill (R1 lesson: (512,4) cap 128 spilled).
// ---------------------------------------------------------------------------
__global__ __launch_bounds__(256, 2) void k_big(const ushort_t* __restrict__ xbf,
                                                const ushort_t* __restrict__ WbT,
                                                const float* __restrict__ CTXT,
                                                ushort_t* __restrict__ hbf) {
    __shared__ __align__(16) ushort_t Bt[2 * 128 * 128];   // 64 KB
    const int tid = threadIdx.x;
    const int lane = tid & 63, w = tid >> 6;               // 4 waves
    const int l15 = lane & 15, quad = lane >> 4;
    const int gidx = blockIdx.x;
    const int by = gidx & 3;                               // xcd = gidx&7
    const int bx = (gidx >> 3) * 2 + ((gidx >> 2) & 1);    // 0..255
    const int m0 = bx * 128, n0 = by * 128;
    const int mr0 = m0 + w * 32 + l15;                     // mt=0 A-row
    const int mr1 = mr0 + 16;                              // mt=1 A-row

    short8 afr[2][2];                                      // [mt][ks]: x row frag
    afr[0][0] = *(const short8*)(xbf + (size_t)mr0 * 64 + quad * 8);
    afr[0][1] = *(const short8*)(xbf + (size_t)mr0 * 64 + 32 + quad * 8);
    afr[1][0] = *(const short8*)(xbf + (size_t)mr1 * 64 + quad * 8);
    afr[1][1] = *(const short8*)(xbf + (size_t)mr1 * 64 + 32 + quad * 8);

    floatx4 acc[2][8];
#pragma unroll
    for (int mt = 0; mt < 2; ++mt)
#pragma unroll
        for (int nt = 0; nt < 8; ++nt) acc[mt][nt] = (floatx4){0.f, 0.f, 0.f, 0.f};

    // staging: granule G = w*512 + q*64 + lane (8 granules/thread, 32 KB/tile)
    // nr = G>>4; k8 = (G&15)^(nr&15)  (XOR swizzle, matched on read side)
    const ushort_t* gq[8];
    ushort_t* lq[8];
#pragma unroll
    for (int q = 0; q < 8; ++q) {
        const int G = w * 512 + q * 64 + lane;
        const int nr = G >> 4;
        const int k8 = (G & 15) ^ (nr & 15);
        gq[q] = WbT + (size_t)(n0 + nr) * 16448 + k8 * 8;
        lq[q] = Bt + w * 4096 + q * 512;                   // wave-uniform base
    }
#pragma unroll
    for (int q = 0; q < 8; ++q) glds16(gq[q], lq[q]);      // tile 0 -> buf 0

    float scv[2][2];                                       // [h][mt]
    scv[0][0] = CTXT[mr0];           scv[0][1] = CTXT[mr1];
    scv[1][0] = CTXT[32768 + mr0];   scv[1][1] = CTXT[32768 + mr1];

    for (int kk = 0; kk < 129; ++kk) {
        const int p = kk & 1;
        __syncthreads();                                   // tile kk resident
        if (kk < 128) {                                    // prefetch tile kk+1
            const size_t koff = (size_t)(kk + 1) * 128;
            const int np = (p ^ 1) * 16384;
#pragma unroll
            for (int q = 0; q < 8; ++q) glds16(gq[q] + koff, lq[q] + np);
        }
        float scn00 = 1.f, scn01 = 1.f, scn10 = 1.f, scn11 = 1.f;
        if (kk + 1 < 128) {
            scn00 = CTXT[(size_t)(2 * kk + 2) * 32768 + mr0];
            scn01 = CTXT[(size_t)(2 * kk + 2) * 32768 + mr1];
            scn10 = CTXT[(size_t)(2 * kk + 3) * 32768 + mr0];
            scn11 = CTXT[(size_t)(2 * kk + 3) * 32768 + mr1];
        }
        const ushort_t* bb = Bt + p * 16384;
        if (kk < 128) {
#pragma unroll
            for (int h = 0; h < 2; ++h) {
#pragma unroll
                for (int ks = 0; ks < 2; ++ks) {
                    short8 a0 = scale8(afr[0][ks], scv[h][0]);
                    short8 a1 = scale8(afr[1][ks], scv[h][1]);
#pragma unroll
                    for (int nt = 0; nt < 8; ++nt) {
                        const int nr = nt * 16 + l15;
                        const char* bpr = (const char*)bb + nr * 256;
                        short8 b = *(const short8*)(bpr + (((h * 8 + ks * 4 + quad) ^ l15) * 16));
                        acc[0][nt] = __builtin_amdgcn_mfma_f32_16x16x32_bf16(a0, b, acc[0][nt], 0, 0, 0);
                        acc[1][nt] = __builtin_amdgcn_mfma_f32_16x16x32_bf16(a1, b, acc[1][nt], 0, 0, 0);
                    }
                }
            }
        } else {                                           // bias block, scale=1
#pragma unroll
            for (int nt = 0; nt < 8; ++nt) {
                const int nr = nt * 16 + l15;
                const char* bpr = (const char*)bb + nr * 256;
                short8 b0 = *(const short8*)(bpr + ((quad ^ l15) * 16));
                short8 b1 = *(const short8*)(bpr + (((4 + quad) ^ l15) * 16));
                acc[0][nt] = __builtin_amdgcn_mfma_f32_16x16x32_bf16(afr[0][0], b0, acc[0][nt], 0, 0, 0);
                acc[0][nt] = __builtin_amdgcn_mfma_f32_16x16x32_bf16(afr[0][1], b1, acc[0][nt], 0, 0, 0);
                acc[1][nt] = __builtin_amdgcn_mfma_f32_16x16x32_bf16(afr[1][0], b0, acc[1][nt], 0, 0, 0);
                acc[1][nt] = __builtin_amdgcn_mfma_f32_16x16x32_bf16(afr[1][1], b1, acc[1][nt], 0, 0, 0);
            }
        }
        scv[0][0] = scn00; scv[0][1] = scn01;
        scv[1][0] = scn10; scv[1][1] = scn11;
    }
    // epilogue: C/D col = n0+nt*16+l15, row = m0 + w*32 + mt*16 + quad*4 + r
#pragma unroll
    for (int mt = 0; mt < 2; ++mt)
#pragma unroll
        for (int nt = 0; nt < 8; ++nt) {
            const int col = n0 + nt * 16 + l15;
#pragma unroll
            for (int r = 0; r < 4; ++r) {
                const int row = m0 + w * 32 + mt * 16 + quad * 4 + r;
                hbf[(size_t)row * 512 + col] = f2bf(fmaxf(acc[mt][nt][r], 0.f));
            }
        }
}

// ---------------------------------------------------------------------------
// Generic bf16 NT GEMM: C[m,n] = sum_k A[m,k]*B[n,k] + bias[n]
// ---------------------------------------------------------------------------
template <bool OUTF32>
__global__ __launch_bounds__(256, 2) void k_gemm_nt(const ushort_t* __restrict__ A,
                                                    const ushort_t* __restrict__ Bm,
                                                    const float* __restrict__ bias,
                                                    ushort_t* __restrict__ outb,
                                                    float* __restrict__ outf,
                                                    int K, int Nst) {
    __shared__ __align__(16) ushort_t At[128 * 72];
    __shared__ __align__(16) ushort_t Bt[128 * 72];
    const int tid = threadIdx.x;
    const int lane = tid & 63, w = tid >> 6;
    const int wm = w & 1, wn = w >> 1;
    const int l15 = lane & 15, quad = lane >> 4;
    const int m0 = blockIdx.x * 128, n0 = blockIdx.y * 128;

    const int r_l = tid >> 1, kh = (tid & 1) * 32;
    const ushort_t* gA = A + (size_t)(m0 + r_l) * K + kh;
    const ushort_t* gB = Bm + (size_t)(n0 + r_l) * K + kh;
    ushort_t* lA = &At[r_l * 72 + kh];
    ushort_t* lB = &Bt[r_l * 72 + kh];

    uint4 ra0 = *(const uint4*)(gA + 0), ra1 = *(const uint4*)(gA + 8);
    uint4 ra2 = *(const uint4*)(gA + 16), ra3 = *(const uint4*)(gA + 24);
    uint4 rb0 = *(const uint4*)(gB + 0), rb1 = *(const uint4*)(gB + 8);
    uint4 rb2 = *(const uint4*)(gB + 16), rb3 = *(const uint4*)(gB + 24);

    floatx4 acc[4][4];
#pragma unroll
    for (int i = 0; i < 4; ++i)
#pragma unroll
        for (int j = 0; j < 4; ++j) acc[i][j] = (floatx4){0.f, 0.f, 0.f, 0.f};

    const int niter = K >> 6;
    for (int kb = 0; kb < niter; ++kb) {
        __syncthreads();
        *(uint4*)(lA + 0) = ra0;  *(uint4*)(lA + 8) = ra1;
        *(uint4*)(lA + 16) = ra2; *(uint4*)(lA + 24) = ra3;
        *(uint4*)(lB + 0) = rb0;  *(uint4*)(lB + 8) = rb1;
        *(uint4*)(lB + 16) = rb2; *(uint4*)(lB + 24) = rb3;
        __syncthreads();
        if (kb + 1 < niter) {
            const ushort_t* ga = gA + (size_t)(kb + 1) * 64;
            const ushort_t* gb = gB + (size_t)(kb + 1) * 64;
            ra0 = *(const uint4*)(ga + 0);  ra1 = *(const uint4*)(ga + 8);
            ra2 = *(const uint4*)(ga + 16); ra3 = *(const uint4*)(ga + 24);
            rb0 = *(const uint4*)(gb + 0);  rb1 = *(const uint4*)(gb + 8);
            rb2 = *(const uint4*)(gb + 16); rb3 = *(const uint4*)(gb + 24);
        }
        short8 av[4][2];
#pragma unroll
        for (int mt = 0; mt < 4; ++mt) {
            const int mr = wm * 64 + mt * 16 + l15;
            av[mt][0] = *(const short8*)(&At[mr * 72 + quad * 8]);
            av[mt][1] = *(const short8*)(&At[mr * 72 + 32 + quad * 8]);
        }
#pragma unroll
        for (int nt = 0; nt < 4; ++nt) {
            const int nr = wn * 64 + nt * 16 + l15;
            short8 b0 = *(const short8*)(&Bt[nr * 72 + quad * 8]);
            short8 b1 = *(const short8*)(&Bt[nr * 72 + 32 + quad * 8]);
#pragma unroll
            for (int mt = 0; mt < 4; ++mt) {
                acc[mt][nt] = __builtin_amdgcn_mfma_f32_16x16x32_bf16(av[mt][0], b0, acc[mt][nt], 0, 0, 0);
                acc[mt][nt] = __builtin_amdgcn_mfma_f32_16x16x32_bf16(av[mt][1], b1, acc[mt][nt], 0, 0, 0);
            }
        }
    }
#pragma unroll
    for (int mt = 0; mt < 4; ++mt)
#pragma unroll
        for (int nt = 0; nt < 4; ++nt) {
            const int col = n0 + wn * 64 + nt * 16 + l15;
            const float bb = bias[col];
#pragma unroll
            for (int r = 0; r < 4; ++r) {
                const int row = m0 + wm * 64 + mt * 16 + quad * 4 + r;
                const float v = acc[mt][nt][r] + bb;
                if (OUTF32) outf[(size_t)row * Nst + col] = v;
                else        outb[(size_t)row * Nst + col] = f2bf(v);
            }
        }
}

// ---------------------------------------------------------------------------
// LayerNorm + residual: z = h + relu( LN(hn)*g + b ), in-place over hbf.
// ---------------------------------------------------------------------------
__global__ __launch_bounds__(256, 1) void k_ln(const ushort_t* __restrict__ hn,
                                               ushort_t* __restrict__ h,
                                               const float* __restrict__ g,
                                               const float* __restrict__ bb) {
    const int tid = threadIdx.x;
    const int lane = tid & 63;
    const int row = blockIdx.x * 4 + (tid >> 6);
    const uint4 hv = *(const uint4*)(hn + (size_t)row * 512 + lane * 8);
    float f[8];
    f[0] = blo(hv.x); f[1] = bhi(hv.x); f[2] = blo(hv.y); f[3] = bhi(hv.y);
    f[4] = blo(hv.z); f[5] = bhi(hv.z); f[6] = blo(hv.w); f[7] = bhi(hv.w);
    float s = 0.f, s2 = 0.f;
#pragma unroll
    for (int j = 0; j < 8; ++j) { s += f[j]; s2 = fmaf(f[j], f[j], s2); }
#pragma unroll
    for (int o = 32; o >= 1; o >>= 1) { s += __shfl_xor(s, o, 64); s2 += __shfl_xor(s2, o, 64); }
    const float mu = s * (1.f / 512.f);
    const float var = s2 * (1.f / 512.f) - mu * mu;
    const float rs = rsqrtf(var + 1e-5f);
    const uint4 hh = *(const uint4*)(h + (size_t)row * 512 + lane * 8);
    float hf[8];
    hf[0] = blo(hh.x); hf[1] = bhi(hh.x); hf[2] = blo(hh.y); hf[3] = bhi(hh.y);
    hf[4] = blo(hh.z); hf[5] = bhi(hh.z); hf[6] = blo(hh.w); hf[7] = bhi(hh.w);
    float4 g0 = *(const float4*)(g + lane * 8);  float4 g1 = *(const float4*)(g + lane * 8 + 4);
    float4 b0 = *(const float4*)(bb + lane * 8); float4 b1 = *(const float4*)(bb + lane * 8 + 4);
    const float gv[8] = {g0.x, g0.y, g0.z, g0.w, g1.x, g1.y, g1.z, g1.w};
    const float bv[8] = {b0.x, b0.y, b0.z, b0.w, b1.x, b1.y, b1.z, b1.w};
    float z[8];
#pragma unroll
    for (int j = 0; j < 8; ++j)
        z[j] = hf[j] + fmaxf((f[j] - mu) * rs * gv[j] + bv[j], 0.f);
    uint4 o;
    o.x = pack2(z[0], z[1]); o.y = pack2(z[2], z[3]);
    o.z = pack2(z[4], z[5]); o.w = pack2(z[6], z[7]);
    *(uint4*)(h + (size_t)row * 512 + lane * 8) = o;
}

// ---------------------------------------------------------------------------
extern "C" void kernel_launch(void* const* d_in, const int* in_sizes, int n_in,
                              void* d_out, int out_size, void* d_ws, size_t ws_size,
                              hipStream_t stream) {
    const float* x    = (const float*)d_in[0];
    const float* Wcc  = (const float*)d_in[1];
    const float* bcc  = (const float*)d_in[2];
    const float* Wic  = (const float*)d_in[3];
    const float* bic  = (const float*)d_in[4];
    const float* Wmap = (const float*)d_in[5];
    const float* bmap = (const float*)d_in[6];
    const float* Whh  = (const float*)d_in[7];
    const float* bhh  = (const float*)d_in[8];
    const float* ln_g = (const float*)d_in[9];
    const float* ln_b = (const float*)d_in[10];
    const float* Who  = (const float*)d_in[11];
    const float* bho  = (const float*)d_in[12];
    float* out = (float*)d_out;

    char* wsb = (char*)d_ws;
    ushort_t* WbT  = (ushort_t*)(wsb);                    // 16,842,752 B + 1 KB pad
    ushort_t* Whhb = (ushort_t*)(wsb + 16843776);         //    524,288
    ushort_t* Whob = (ushort_t*)(wsb + 17368064);         //    131,072
    ushort_t* xbf  = (ushort_t*)(wsb + 17499136);         //  4,194,304
    float*    CTXT = (float*)   (wsb + 21693440);         // 33,554,432
    ushort_t* hbf  = (ushort_t*)(wsb + 55247872);         // 33,554,432 (h, then z)
    ushort_t* hnbf = (ushort_t*)(wsb + 88802304);         // 33,554,432 -> ~122 MB

    k_fused<<<1052, 256, 0, stream>>>(x, Wcc, bcc, Wic, bic, Wmap, bmap, Whh, Who,
                                      WbT, Whhb, Whob, xbf, CTXT, out + 4194304);
    k_big<<<1024, 256, 0, stream>>>(xbf, WbT, CTXT, hbf);
    k_gemm_nt<false><<<dim3(256, 4), 256, 0, stream>>>(hbf, Whhb, bhh, hnbf, nullptr, 512, 512);
    k_ln<<<8192, 256, 0, stream>>>(hnbf, hbf, ln_g, ln_b);
    k_gemm_nt<true><<<dim3(256, 1), 256, 0, stream>>>(hbf, Whob, bho, nullptr, out, 512, 128);
}

// Round 4
// 838.762 us; speedup vs baseline: 2.0326x; 1.0114x over previous
//
#include <hip/hip_runtime.h>

// ---------------------------------------------------------------------------
// InputMapCTRNN: T=256, B=128, I=64, C=256, H=512, O=128, ALPHA=1, EPS=1e-5
//
// h[t,b,n] = relu( sum_c ctx[t,b,c]*S_c + S_bias ),
//   S_c[m,n] = sum_i x[m,i]*WbT[n, c*64+i]  -> one MFMA GEMM M=32768,N=512,
//   K=16448. Scale folded into A: ahat[m, c*64+i] = bf16(ctx[m,c]*x[m,i])
//   built per-fragment in registers -> pure MFMA accumulation chain, LDS
//   double-buffered glds staging of B.
//
// R1 (FAILED): mt=2 at 512thr/(512,4): VGPR cap 128 -> acc spill (WRITE_SIZE
//   1.27GB scratch). R3: mt=2 at 256thr/(256,2): 500us, MfmaUtil 52.5%,
//   VGPR=88, no spill. Model: MFMA 1242cyc vs elapsed 2328cyc/block-iter;
//   LDS-read 128KB/block-iter fixed regardless of mt (B volume = n-range x BK
//   per wave). -> raise mt.
// R4: mt=4 (wave 64m x 128n, block 256x128, grid 512). Each B fragment feeds
//   4 MFMAs; MFMA pipe demand 2483cyc/block-iter now dominates LDS (~1024) and
//   VALU (~900). acc 128 + afr 32 + temps ~220 VGPR < 256 cap.
// ---------------------------------------------------------------------------

typedef unsigned int  uint_t;
typedef unsigned short ushort_t;
typedef __attribute__((ext_vector_type(8))) short  short8;
typedef __attribute__((ext_vector_type(4))) short  short4v;
typedef __attribute__((ext_vector_type(4))) float  floatx4;

__device__ __forceinline__ ushort_t f2bf(float f) {
    uint_t u = __float_as_uint(f);
    u = (u + 0x7fffu + ((u >> 16) & 1u)) >> 16;   // RNE
    return (ushort_t)u;
}
__device__ __forceinline__ uint_t pack2(float a, float b) {
    return (uint_t)f2bf(a) | ((uint_t)f2bf(b) << 16);
}
__device__ __forceinline__ float blo(uint_t u) { return __uint_as_float(u << 16); }
__device__ __forceinline__ float bhi(uint_t u) { return __uint_as_float(u & 0xffff0000u); }

__device__ __forceinline__ void glds16(const void* g, void* l) {
    __builtin_amdgcn_global_load_lds(
        (const __attribute__((address_space(1))) unsigned int*)g,
        (__attribute__((address_space(3))) unsigned int*)l, 16, 0, 0);
}

// scale 8 packed bf16 by fp32 scalar, repack via v_cvt_pk_bf16_f32 (RNE)
__device__ __forceinline__ short8 scale8(short8 a, float s) {
    union { short8 v; uint_t u[4]; } in, out;
    in.v = a;
#pragma unroll
    for (int q = 0; q < 4; ++q) {
        float lo = blo(in.u[q]) * s;
        float hi = bhi(in.u[q]) * s;
        uint_t r;
        asm("v_cvt_pk_bf16_f32 %0, %1, %2" : "=v"(r) : "v"(lo), "v"(hi));
        out.u[q] = r;
    }
    return out.v;
}

// ---------------------------------------------------------------------------
// FUSED: blocks 0..7 = sequential ctx recurrence (K=320 MFMA, 1 barrier/step,
// LDS double-buffer, x read fp32 from input). blocks 8..1051 = prep (WbT
// transpose+cvt, Whh/Who/x -> bf16) — independent, hides under recurrence.
// ---------------------------------------------------------------------------
__global__ __launch_bounds__(256, 1) void k_fused(
        const float* __restrict__ x, const float* __restrict__ Wcc,
        const float* __restrict__ bcc, const float* __restrict__ Wic,
        const float* __restrict__ bic, const float* __restrict__ Wmap,
        const float* __restrict__ bmap, const float* __restrict__ Whh,
        const float* __restrict__ Who,
        ushort_t* WbT, ushort_t* Whhb, ushort_t* Whob, ushort_t* xbf,
        float* __restrict__ CTXT, float* __restrict__ ctx_out) {
    __shared__ __align__(16) char smem[32896];   // union: prep 32896 B / rec 20480 B
    const int tid = threadIdx.x;
    const int bid = blockIdx.x;

    if (bid >= 8) {
        const int pb = bid - 8;
        if (pb < 512) {                      // WbT[n][c*64+i] = Wmap[n*64+i][c]
            float* tl = (float*)smem;        // 32*257 floats
            const int n = pb;
            for (int p = 0; p < 2; ++p) {
                if (p) __syncthreads();
#pragma unroll
                for (int k = 0; k < 32; ++k)
                    tl[k * 257 + tid] = Wmap[(size_t)(n * 64 + p * 32 + k) * 256 + tid];
                __syncthreads();
#pragma unroll
                for (int k2 = 0; k2 < 32; ++k2) {
                    int o = k2 * 256 + tid;
                    int il = o & 31, c = o >> 5;
                    WbT[(size_t)n * 16448 + c * 64 + p * 32 + il] = f2bf(tl[il * 257 + c]);
                }
            }
            if (tid < 64) WbT[(size_t)n * 16448 + 16384 + tid] = f2bf(bmap[n * 64 + tid]);
        } else if (pb < 528) {
            size_t base = (size_t)(pb - 512) * 16384;
#pragma unroll
            for (int k = 0; k < 64; ++k) { size_t i = base + k * 256 + tid; Whhb[i] = f2bf(Whh[i]); }
        } else if (pb < 532) {
            size_t base = (size_t)(pb - 528) * 16384;
#pragma unroll
            for (int k = 0; k < 64; ++k) { size_t i = base + k * 256 + tid; Whob[i] = f2bf(Who[i]); }
        } else {
            size_t base = (size_t)(pb - 532) * 4096;
#pragma unroll
            for (int k = 0; k < 16; ++k) { size_t i = base + k * 256 + tid; xbf[i] = f2bf(x[i]); }
        }
        return;
    }

    // ---------------- recurrence: block g owns samples [g*16, g*16+16) ------
    char* bufs = smem;                          // 2 x 10240 B
    const int g = bid;
    const int lane = tid & 63, w = tid >> 6;
    const int l15 = lane & 15, quad = lane >> 4;
    const int bq = tid >> 4, o4 = tid & 15;     // x-staging role

    // A-fragments: Wcc (kb 0..7) + Wic (kb 8..9); row j = w*64+mt*16+l15
    short8 wf[4][8], wi[4][2];
#pragma unroll
    for (int mt = 0; mt < 4; ++mt) {
        const int j = w * 64 + mt * 16 + l15;
#pragma unroll
        for (int kb = 0; kb < 8; ++kb) {
            const float* src = Wcc + (size_t)j * 256 + kb * 32 + quad * 8;
            float4 a = *(const float4*)src;
            float4 b = *(const float4*)(src + 4);
            short8 s;
            s[0] = (short)f2bf(a.x); s[1] = (short)f2bf(a.y);
            s[2] = (short)f2bf(a.z); s[3] = (short)f2bf(a.w);
            s[4] = (short)f2bf(b.x); s[5] = (short)f2bf(b.y);
            s[6] = (short)f2bf(b.z); s[7] = (short)f2bf(b.w);
            wf[mt][kb] = s;
        }
#pragma unroll
        for (int kb = 0; kb < 2; ++kb) {
            const float* src = Wic + (size_t)j * 64 + kb * 32 + quad * 8;
            float4 a = *(const float4*)src;
            float4 b = *(const float4*)(src + 4);
            short8 s;
            s[0] = (short)f2bf(a.x); s[1] = (short)f2bf(a.y);
            s[2] = (short)f2bf(a.z); s[3] = (short)f2bf(a.w);
            s[4] = (short)f2bf(b.x); s[5] = (short)f2bf(b.y);
            s[6] = (short)f2bf(b.z); s[7] = (short)f2bf(b.w);
            wi[mt][kb] = s;
        }
    }
    float4 bias[4];
#pragma unroll
    for (int mt = 0; mt < 4; ++mt) {
        const int j0 = w * 64 + mt * 16 + quad * 4;
        float4 b1 = *(const float4*)(bic + j0);
        float4 b2 = *(const float4*)(bcc + j0);
        bias[mt] = (float4){b1.x + b2.x, b1.y + b2.y, b1.z + b2.z, b1.w + b2.w};
    }
    // init buf0: ctx=0 (granule rows 0..31), x_0 (rows 32..39)
    *(uint4*)(bufs + tid * 16) = (uint4){0, 0, 0, 0};
    *(uint4*)(bufs + (tid + 256) * 16) = (uint4){0, 0, 0, 0};
    {
        float4 xv = *(const float4*)(x + (size_t)(g * 16 + bq) * 64 + o4 * 4);
        short4v s4;
        s4[0] = (short)f2bf(xv.x); s4[1] = (short)f2bf(xv.y);
        s4[2] = (short)f2bf(xv.z); s4[3] = (short)f2bf(xv.w);
        *(short4v*)(bufs + (32 + (o4 >> 1)) * 256 + bq * 16 + (o4 & 1) * 8) = s4;
    }
    float4 y[4];
#pragma unroll
    for (int mt = 0; mt < 4; ++mt) y[mt] = (float4){0.f, 0.f, 0.f, 0.f};
    __syncthreads();

    int p = 0;
#pragma unroll 1
    for (int t = 0; t < 256; ++t) {
        char* bp = bufs + p * 10240;
        char* bn = bufs + (p ^ 1) * 10240;
        // CTXT[c][t*128 + b] = ctx entering step t (= y)
#pragma unroll
        for (int mt = 0; mt < 4; ++mt) {
            const int j0 = w * 64 + mt * 16 + quad * 4;
#pragma unroll
            for (int r = 0; r < 4; ++r)
                CTXT[(size_t)(j0 + r) * 32768 + t * 128 + g * 16 + l15] = (&y[mt].x)[r];
        }
        float4 xv;
        if (t < 255)
            xv = *(const float4*)(x + (size_t)((t + 1) * 128 + g * 16 + bq) * 64 + o4 * 4);
        floatx4 acc[4];
#pragma unroll
        for (int mt = 0; mt < 4; ++mt) acc[mt] = (floatx4){0.f, 0.f, 0.f, 0.f};
#pragma unroll
        for (int kb = 0; kb < 8; ++kb) {
            short8 bf = *(const short8*)(bp + (kb * 4 + quad) * 256 + l15 * 16);
#pragma unroll
            for (int mt = 0; mt < 4; ++mt)
                acc[mt] = __builtin_amdgcn_mfma_f32_16x16x32_bf16(wf[mt][kb], bf, acc[mt], 0, 0, 0);
        }
#pragma unroll
        for (int kb = 0; kb < 2; ++kb) {
            short8 bf = *(const short8*)(bp + ((8 + kb) * 4 + quad) * 256 + l15 * 16);
#pragma unroll
            for (int mt = 0; mt < 4; ++mt)
                acc[mt] = __builtin_amdgcn_mfma_f32_16x16x32_bf16(wi[mt][kb], bf, acc[mt], 0, 0, 0);
        }
#pragma unroll
        for (int mt = 0; mt < 4; ++mt) {
            y[mt].x = fmaxf(acc[mt][0] + bias[mt].x, 0.f);
            y[mt].y = fmaxf(acc[mt][1] + bias[mt].y, 0.f);
            y[mt].z = fmaxf(acc[mt][2] + bias[mt].z, 0.f);
            y[mt].w = fmaxf(acc[mt][3] + bias[mt].w, 0.f);
        }
        if (t < 255) {
#pragma unroll
            for (int mt = 0; mt < 4; ++mt) {
                const int c0 = w * 64 + mt * 16 + quad * 4;
                short4v s4;
                s4[0] = (short)f2bf(y[mt].x); s4[1] = (short)f2bf(y[mt].y);
                s4[2] = (short)f2bf(y[mt].z); s4[3] = (short)f2bf(y[mt].w);
                *(short4v*)(bn + (c0 >> 3) * 256 + l15 * 16 + (c0 & 7) * 2) = s4;
            }
            short4v s4;
            s4[0] = (short)f2bf(xv.x); s4[1] = (short)f2bf(xv.y);
            s4[2] = (short)f2bf(xv.z); s4[3] = (short)f2bf(xv.w);
            *(short4v*)(bn + (32 + (o4 >> 1)) * 256 + bq * 16 + (o4 & 1) * 8) = s4;
        }
        __syncthreads();
        p ^= 1;
    }
#pragma unroll
    for (int mt = 0; mt < 4; ++mt) {
        const int j0 = w * 64 + mt * 16 + quad * 4;
#pragma unroll
        for (int r = 0; r < 4; ++r)
            ctx_out[(size_t)(g * 16 + l15) * 256 + j0 + r] = (&y[mt].x)[r];
    }
}

// ---------------------------------------------------------------------------
// BIG GEMM: M=32768,N=512,K=16448, scale folded into A-fragments.
// 256 thr / 4 waves, block tile 256x128, wave tile 64m x 128n (mt=4: each
// LDS B-fragment feeds 4 MFMAs; B-read volume per wave is fixed at
// n-range x BK, so mt=4 doubles FLOPs against constant LDS traffic).
// BK=128, LDS DOUBLE-buffer (2x32 KB), glds(16B) for tile kk+1 issued right
// after the single per-iter barrier -> latency hidden behind compute.
// 1D grid 512, XCD swizzle: by = gidx&3 (one WbT n-slice per XCD L2).
// __launch_bounds__(256,2): 2 blocks/CU (LDS-limited), VGPR cap 256;
// acc 128 + afr 32 + temps ~ 220 fits (R3 measured only 88 at mt=2).
// ---------------------------------------------------------------------------
__global__ __launch_bounds__(256, 2) void k_big(const ushort_t* __restrict__ xbf,
                                                const ushort_t* __restrict__ WbT,
                                                const float* __restrict__ CTXT,
                                                ushort_t* __restrict__ hbf) {
    __shared__ __align__(16) ushort_t Bt[2 * 128 * 128];   // 64 KB
    const int tid = threadIdx.x;
    const int lane = tid & 63, w = tid >> 6;               // 4 waves
    const int l15 = lane & 15, quad = lane >> 4;
    const int gidx = blockIdx.x;
    const int by = gidx & 3;                               // xcd = gidx&7
    const int bx = (gidx >> 3) * 2 + ((gidx >> 2) & 1);    // 0..127
    const int m0 = bx * 256, n0 = by * 128;

    int mr[4];
#pragma unroll
    for (int mt = 0; mt < 4; ++mt) mr[mt] = m0 + w * 64 + mt * 16 + l15;

    short8 afr[4][2];                                      // [mt][ks]: x row frag
#pragma unroll
    for (int mt = 0; mt < 4; ++mt) {
        afr[mt][0] = *(const short8*)(xbf + (size_t)mr[mt] * 64 + quad * 8);
        afr[mt][1] = *(const short8*)(xbf + (size_t)mr[mt] * 64 + 32 + quad * 8);
    }

    floatx4 acc[4][8];
#pragma unroll
    for (int mt = 0; mt < 4; ++mt)
#pragma unroll
        for (int nt = 0; nt < 8; ++nt) acc[mt][nt] = (floatx4){0.f, 0.f, 0.f, 0.f};

    // staging: granule G = w*512 + q*64 + lane (8 granules/thread, 32 KB/tile)
    // nr = G>>4; k8 = (G&15)^(nr&15)  (XOR swizzle, matched on read side)
    const ushort_t* gq[8];
    ushort_t* lq[8];
#pragma unroll
    for (int q = 0; q < 8; ++q) {
        const int G = w * 512 + q * 64 + lane;
        const int nr = G >> 4;
        const int k8 = (G & 15) ^ (nr & 15);
        gq[q] = WbT + (size_t)(n0 + nr) * 16448 + k8 * 8;
        lq[q] = Bt + w * 4096 + q * 512;                   // wave-uniform base
    }
#pragma unroll
    for (int q = 0; q < 8; ++q) glds16(gq[q], lq[q]);      // tile 0 -> buf 0

    float scv[2][4];                                       // [h][mt]
#pragma unroll
    for (int mt = 0; mt < 4; ++mt) {
        scv[0][mt] = CTXT[mr[mt]];
        scv[1][mt] = CTXT[32768 + mr[mt]];
    }

    for (int kk = 0; kk < 129; ++kk) {
        const int p = kk & 1;
        __syncthreads();                                   // tile kk resident
        if (kk < 128) {                                    // prefetch tile kk+1
            const size_t koff = (size_t)(kk + 1) * 128;
            const int np = (p ^ 1) * 16384;
#pragma unroll
            for (int q = 0; q < 8; ++q) glds16(gq[q] + koff, lq[q] + np);
        }
        float scn[2][4];
#pragma unroll
        for (int h = 0; h < 2; ++h)
#pragma unroll
            for (int mt = 0; mt < 4; ++mt) scn[h][mt] = 1.f;
        if (kk + 1 < 128) {
#pragma unroll
            for (int mt = 0; mt < 4; ++mt) {
                scn[0][mt] = CTXT[(size_t)(2 * kk + 2) * 32768 + mr[mt]];
                scn[1][mt] = CTXT[(size_t)(2 * kk + 3) * 32768 + mr[mt]];
            }
        }
        const ushort_t* bb = Bt + p * 16384;
        if (kk < 128) {
#pragma unroll
            for (int h = 0; h < 2; ++h) {
#pragma unroll
                for (int ks = 0; ks < 2; ++ks) {
                    short8 a0 = scale8(afr[0][ks], scv[h][0]);
                    short8 a1 = scale8(afr[1][ks], scv[h][1]);
                    short8 a2 = scale8(afr[2][ks], scv[h][2]);
                    short8 a3 = scale8(afr[3][ks], scv[h][3]);
#pragma unroll
                    for (int nt = 0; nt < 8; ++nt) {
                        const int nr2 = nt * 16 + l15;
                        const char* bpr = (const char*)bb + nr2 * 256;
                        short8 b = *(const short8*)(bpr + (((h * 8 + ks * 4 + quad) ^ l15) * 16));
                        acc[0][nt] = __builtin_amdgcn_mfma_f32_16x16x32_bf16(a0, b, acc[0][nt], 0, 0, 0);
                        acc[1][nt] = __builtin_amdgcn_mfma_f32_16x16x32_bf16(a1, b, acc[1][nt], 0, 0, 0);
                        acc[2][nt] = __builtin_amdgcn_mfma_f32_16x16x32_bf16(a2, b, acc[2][nt], 0, 0, 0);
                        acc[3][nt] = __builtin_amdgcn_mfma_f32_16x16x32_bf16(a3, b, acc[3][nt], 0, 0, 0);
                    }
                }
            }
        } else {                                           // bias block, scale=1
#pragma unroll
            for (int ks = 0; ks < 2; ++ks) {
#pragma unroll
                for (int nt = 0; nt < 8; ++nt) {
                    const int nr2 = nt * 16 + l15;
                    const char* bpr = (const char*)bb + nr2 * 256;
                    short8 b = *(const short8*)(bpr + (((ks * 4 + quad) ^ l15) * 16));
#pragma unroll
                    for (int mt = 0; mt < 4; ++mt)
                        acc[mt][nt] = __builtin_amdgcn_mfma_f32_16x16x32_bf16(afr[mt][ks], b, acc[mt][nt], 0, 0, 0);
                }
            }
        }
#pragma unroll
        for (int h = 0; h < 2; ++h)
#pragma unroll
            for (int mt = 0; mt < 4; ++mt) scv[h][mt] = scn[h][mt];
    }
    // epilogue: C/D col = n0+nt*16+l15, row = m0 + w*64 + mt*16 + quad*4 + r
#pragma unroll
    for (int mt = 0; mt < 4; ++mt)
#pragma unroll
        for (int nt = 0; nt < 8; ++nt) {
            const int col = n0 + nt * 16 + l15;
#pragma unroll
            for (int r = 0; r < 4; ++r) {
                const int row = m0 + w * 64 + mt * 16 + quad * 4 + r;
                hbf[(size_t)row * 512 + col] = f2bf(fmaxf(acc[mt][nt][r], 0.f));
            }
        }
}

// ---------------------------------------------------------------------------
// Generic bf16 NT GEMM: C[m,n] = sum_k A[m,k]*B[n,k] + bias[n]
// ---------------------------------------------------------------------------
template <bool OUTF32>
__global__ __launch_bounds__(256, 2) void k_gemm_nt(const ushort_t* __restrict__ A,
                                                    const ushort_t* __restrict__ Bm,
                                                    const float* __restrict__ bias,
                                                    ushort_t* __restrict__ outb,
                                                    float* __restrict__ outf,
                                                    int K, int Nst) {
    __shared__ __align__(16) ushort_t At[128 * 72];
    __shared__ __align__(16) ushort_t Bt[128 * 72];
    const int tid = threadIdx.x;
    const int lane = tid & 63, w = tid >> 6;
    const int wm = w & 1, wn = w >> 1;
    const int l15 = lane & 15, quad = lane >> 4;
    const int m0 = blockIdx.x * 128, n0 = blockIdx.y * 128;

    const int r_l = tid >> 1, kh = (tid & 1) * 32;
    const ushort_t* gA = A + (size_t)(m0 + r_l) * K + kh;
    const ushort_t* gB = Bm + (size_t)(n0 + r_l) * K + kh;
    ushort_t* lA = &At[r_l * 72 + kh];
    ushort_t* lB = &Bt[r_l * 72 + kh];

    uint4 ra0 = *(const uint4*)(gA + 0), ra1 = *(const uint4*)(gA + 8);
    uint4 ra2 = *(const uint4*)(gA + 16), ra3 = *(const uint4*)(gA + 24);
    uint4 rb0 = *(const uint4*)(gB + 0), rb1 = *(const uint4*)(gB + 8);
    uint4 rb2 = *(const uint4*)(gB + 16), rb3 = *(const uint4*)(gB + 24);

    floatx4 acc[4][4];
#pragma unroll
    for (int i = 0; i < 4; ++i)
#pragma unroll
        for (int j = 0; j < 4; ++j) acc[i][j] = (floatx4){0.f, 0.f, 0.f, 0.f};

    const int niter = K >> 6;
    for (int kb = 0; kb < niter; ++kb) {
        __syncthreads();
        *(uint4*)(lA + 0) = ra0;  *(uint4*)(lA + 8) = ra1;
        *(uint4*)(lA + 16) = ra2; *(uint4*)(lA + 24) = ra3;
        *(uint4*)(lB + 0) = rb0;  *(uint4*)(lB + 8) = rb1;
        *(uint4*)(lB + 16) = rb2; *(uint4*)(lB + 24) = rb3;
        __syncthreads();
        if (kb + 1 < niter) {
            const ushort_t* ga = gA + (size_t)(kb + 1) * 64;
            const ushort_t* gb = gB + (size_t)(kb + 1) * 64;
            ra0 = *(const uint4*)(ga + 0);  ra1 = *(const uint4*)(ga + 8);
            ra2 = *(const uint4*)(ga + 16); ra3 = *(const uint4*)(ga + 24);
            rb0 = *(const uint4*)(gb + 0);  rb1 = *(const uint4*)(gb + 8);
            rb2 = *(const uint4*)(gb + 16); rb3 = *(const uint4*)(gb + 24);
        }
        short8 av[4][2];
#pragma unroll
        for (int mt = 0; mt < 4; ++mt) {
            const int mr2 = wm * 64 + mt * 16 + l15;
            av[mt][0] = *(const short8*)(&At[mr2 * 72 + quad * 8]);
            av[mt][1] = *(const short8*)(&At[mr2 * 72 + 32 + quad * 8]);
        }
#pragma unroll
        for (int nt = 0; nt < 4; ++nt) {
            const int nr = wn * 64 + nt * 16 + l15;
            short8 b0 = *(const short8*)(&Bt[nr * 72 + quad * 8]);
            short8 b1 = *(const short8*)(&Bt[nr * 72 + 32 + quad * 8]);
#pragma unroll
            for (int mt = 0; mt < 4; ++mt) {
                acc[mt][nt] = __builtin_amdgcn_mfma_f32_16x16x32_bf16(av[mt][0], b0, acc[mt][nt], 0, 0, 0);
                acc[mt][nt] = __builtin_amdgcn_mfma_f32_16x16x32_bf16(av[mt][1], b1, acc[mt][nt], 0, 0, 0);
            }
        }
    }
#pragma unroll
    for (int mt = 0; mt < 4; ++mt)
#pragma unroll
        for (int nt = 0; nt < 4; ++nt) {
            const int col = n0 + wn * 64 + nt * 16 + l15;
            const float bb = bias[col];
#pragma unroll
            for (int r = 0; r < 4; ++r) {
                const int row = m0 + wm * 64 + mt * 16 + quad * 4 + r;
                const float v = acc[mt][nt][r] + bb;
                if (OUTF32) outf[(size_t)row * Nst + col] = v;
                else        outb[(size_t)row * Nst + col] = f2bf(v);
            }
        }
}

// ---------------------------------------------------------------------------
// LayerNorm + residual: z = h + relu( LN(hn)*g + b ), in-place over hbf.
// ---------------------------------------------------------------------------
__global__ __launch_bounds__(256, 1) void k_ln(const ushort_t* __restrict__ hn,
                                               ushort_t* __restrict__ h,
                                               const float* __restrict__ g,
                                               const float* __restrict__ bb) {
    const int tid = threadIdx.x;
    const int lane = tid & 63;
    const int row = blockIdx.x * 4 + (tid >> 6);
    const uint4 hv = *(const uint4*)(hn + (size_t)row * 512 + lane * 8);
    float f[8];
    f[0] = blo(hv.x); f[1] = bhi(hv.x); f[2] = blo(hv.y); f[3] = bhi(hv.y);
    f[4] = blo(hv.z); f[5] = bhi(hv.z); f[6] = blo(hv.w); f[7] = bhi(hv.w);
    float s = 0.f, s2 = 0.f;
#pragma unroll
    for (int j = 0; j < 8; ++j) { s += f[j]; s2 = fmaf(f[j], f[j], s2); }
#pragma unroll
    for (int o = 32; o >= 1; o >>= 1) { s += __shfl_xor(s, o, 64); s2 += __shfl_xor(s2, o, 64); }
    const float mu = s * (1.f / 512.f);
    const float var = s2 * (1.f / 512.f) - mu * mu;
    const float rs = rsqrtf(var + 1e-5f);
    const uint4 hh = *(const uint4*)(h + (size_t)row * 512 + lane * 8);
    float hf[8];
    hf[0] = blo(hh.x); hf[1] = bhi(hh.x); hf[2] = blo(hh.y); hf[3] = bhi(hh.y);
    hf[4] = blo(hh.z); hf[5] = bhi(hh.z); hf[6] = blo(hh.w); hf[7] = bhi(hh.w);
    float4 g0 = *(const float4*)(g + lane * 8);  float4 g1 = *(const float4*)(g + lane * 8 + 4);
    float4 b0 = *(const float4*)(bb + lane * 8); float4 b1 = *(const float4*)(bb + lane * 8 + 4);
    const float gv[8] = {g0.x, g0.y, g0.z, g0.w, g1.x, g1.y, g1.z, g1.w};
    const float bv[8] = {b0.x, b0.y, b0.z, b0.w, b1.x, b1.y, b1.z, b1.w};
    float z[8];
#pragma unroll
    for (int j = 0; j < 8; ++j)
        z[j] = hf[j] + fmaxf((f[j] - mu) * rs * gv[j] + bv[j], 0.f);
    uint4 o;
    o.x = pack2(z[0], z[1]); o.y = pack2(z[2], z[3]);
    o.z = pack2(z[4], z[5]); o.w = pack2(z[6], z[7]);
    *(uint4*)(h + (size_t)row * 512 + lane * 8) = o;
}

// ---------------------------------------------------------------------------
extern "C" void kernel_launch(void* const* d_in, const int* in_sizes, int n_in,
                              void* d_out, int out_size, void* d_ws, size_t ws_size,
                              hipStream_t stream) {
    const float* x    = (const float*)d_in[0];
    const float* Wcc  = (const float*)d_in[1];
    const float* bcc  = (const float*)d_in[2];
    const float* Wic  = (const float*)d_in[3];
    const float* bic  = (const float*)d_in[4];
    const float* Wmap = (const float*)d_in[5];
    const float* bmap = (const float*)d_in[6];
    const float* Whh  = (const float*)d_in[7];
    const float* bhh  = (const float*)d_in[8];
    const float* ln_g = (const float*)d_in[9];
    const float* ln_b = (const float*)d_in[10];
    const float* Who  = (const float*)d_in[11];
    const float* bho  = (const float*)d_in[12];
    float* out = (float*)d_out;

    char* wsb = (char*)d_ws;
    ushort_t* WbT  = (ushort_t*)(wsb);                    // 16,842,752 B + 1 KB pad
    ushort_t* Whhb = (ushort_t*)(wsb + 16843776);         //    524,288
    ushort_t* Whob = (ushort_t*)(wsb + 17368064);         //    131,072
    ushort_t* xbf  = (ushort_t*)(wsb + 17499136);         //  4,194,304
    float*    CTXT = (float*)   (wsb + 21693440);         // 33,554,432
    ushort_t* hbf  = (ushort_t*)(wsb + 55247872);         // 33,554,432 (h, then z)
    ushort_t* hnbf = (ushort_t*)(wsb + 88802304);         // 33,554,432 -> ~122 MB

    k_fused<<<1052, 256, 0, stream>>>(x, Wcc, bcc, Wic, bic, Wmap, bmap, Whh, Who,
                                      WbT, Whhb, Whob, xbf, CTXT, out + 4194304);
    k_big<<<512, 256, 0, stream>>>(xbf, WbT, CTXT, hbf);
    k_gemm_nt<false><<<dim3(256, 4), 256, 0, stream>>>(hbf, Whhb, bhh, hnbf, nullptr, 512, 512);
    k_ln<<<8192, 256, 0, stream>>>(hnbf, hbf, ln_g, ln_b);
    k_gemm_nt<true><<<dim3(256, 1), 256, 0, stream>>>(hbf, Whob, bho, nullptr, out, 512, 128);
}

// Round 5
// 788.622 us; speedup vs baseline: 2.1618x; 1.0636x over previous
//
#include <hip/hip_runtime.h>

// ---------------------------------------------------------------------------
// InputMapCTRNN: T=256, B=128, I=64, C=256, H=512, O=128, ALPHA=1, EPS=1e-5
//
// h[t,b,n] = relu( sum_c ctx[t,b,c]*S_c + S_bias ),
//   S_c[m,n] = sum_i x[m,i]*WbT[n, c*64+i]  -> one MFMA GEMM M=32768,N=512,
//   K=16448. Scale folded into A: ahat[m, c*64+i] = bf16(ctx[m,c]*x[m,i]).
//
// R3: mt=2, 500us, MfmaUtil 52.5% (88 arch + 64 agpr). Per-SIMD model:
//   elapsed 4657cyc/iter, MFMA 2483 (53%), LDS ~3000, VALU 1956.
// R4 (FAILED): mt=4 spilled ~20MB: acc=128 AGPR leaves 256-128=128 arch cap;
//   arch side needed ~145. Spill shares vmcnt with global_load_lds -> every
//   reload drains the B prefetch queue (MfmaUtil AND VALUBusy both fell).
// R5: mt=4 with arch diet (~100 arch): gq[8]->gq[4]+const offset (q and q+4
//   granules share XOR phase, differ by exactly 16 B-rows); CTXT repacked as
//   float2 pairs (CTXT2[c>>1][m][c&1]) so per-iter scale loads are 4 dwordx2
//   off one base pointer with immediate offsets. MFMA demand 4966cyc/SIMD-iter
//   now the dominant pipe (LDS 3000, VALU ~3600).
// ---------------------------------------------------------------------------

typedef unsigned int  uint_t;
typedef unsigned short ushort_t;
typedef __attribute__((ext_vector_type(8))) short  short8;
typedef __attribute__((ext_vector_type(4))) short  short4v;
typedef __attribute__((ext_vector_type(4))) float  floatx4;

__device__ __forceinline__ ushort_t f2bf(float f) {
    uint_t u = __float_as_uint(f);
    u = (u + 0x7fffu + ((u >> 16) & 1u)) >> 16;   // RNE
    return (ushort_t)u;
}
__device__ __forceinline__ uint_t pack2(float a, float b) {
    return (uint_t)f2bf(a) | ((uint_t)f2bf(b) << 16);
}
__device__ __forceinline__ float blo(uint_t u) { return __uint_as_float(u << 16); }
__device__ __forceinline__ float bhi(uint_t u) { return __uint_as_float(u & 0xffff0000u); }

__device__ __forceinline__ void glds16(const void* g, void* l) {
    __builtin_amdgcn_global_load_lds(
        (const __attribute__((address_space(1))) unsigned int*)g,
        (__attribute__((address_space(3))) unsigned int*)l, 16, 0, 0);
}

// scale 8 packed bf16 by fp32 scalar, repack via v_cvt_pk_bf16_f32 (RNE)
__device__ __forceinline__ short8 scale8(short8 a, float s) {
    union { short8 v; uint_t u[4]; } in, out;
    in.v = a;
#pragma unroll
    for (int q = 0; q < 4; ++q) {
        float lo = blo(in.u[q]) * s;
        float hi = bhi(in.u[q]) * s;
        uint_t r;
        asm("v_cvt_pk_bf16_f32 %0, %1, %2" : "=v"(r) : "v"(lo), "v"(hi));
        out.u[q] = r;
    }
    return out.v;
}

// ---------------------------------------------------------------------------
// FUSED: blocks 0..7 = sequential ctx recurrence (K=320 MFMA, 1 barrier/step,
// LDS double-buffer, x read fp32 from input). blocks 8..1051 = prep (WbT
// transpose+cvt, Whh/Who/x -> bf16) — independent, hides under recurrence.
// CTXT layout (R5): CTXT2[c>>1][m][c&1] (pair-rows of 65536 floats) so k_big
// loads both h-scales of a row as one float2.
// ---------------------------------------------------------------------------
__global__ __launch_bounds__(256, 1) void k_fused(
        const float* __restrict__ x, const float* __restrict__ Wcc,
        const float* __restrict__ bcc, const float* __restrict__ Wic,
        const float* __restrict__ bic, const float* __restrict__ Wmap,
        const float* __restrict__ bmap, const float* __restrict__ Whh,
        const float* __restrict__ Who,
        ushort_t* WbT, ushort_t* Whhb, ushort_t* Whob, ushort_t* xbf,
        float* __restrict__ CTXT, float* __restrict__ ctx_out) {
    __shared__ __align__(16) char smem[32896];   // union: prep 32896 B / rec 20480 B
    const int tid = threadIdx.x;
    const int bid = blockIdx.x;

    if (bid >= 8) {
        const int pb = bid - 8;
        if (pb < 512) {                      // WbT[n][c*64+i] = Wmap[n*64+i][c]
            float* tl = (float*)smem;        // 32*257 floats
            const int n = pb;
            for (int p = 0; p < 2; ++p) {
                if (p) __syncthreads();
#pragma unroll
                for (int k = 0; k < 32; ++k)
                    tl[k * 257 + tid] = Wmap[(size_t)(n * 64 + p * 32 + k) * 256 + tid];
                __syncthreads();
#pragma unroll
                for (int k2 = 0; k2 < 32; ++k2) {
                    int o = k2 * 256 + tid;
                    int il = o & 31, c = o >> 5;
                    WbT[(size_t)n * 16448 + c * 64 + p * 32 + il] = f2bf(tl[il * 257 + c]);
                }
            }
            if (tid < 64) WbT[(size_t)n * 16448 + 16384 + tid] = f2bf(bmap[n * 64 + tid]);
        } else if (pb < 528) {
            size_t base = (size_t)(pb - 512) * 16384;
#pragma unroll
            for (int k = 0; k < 64; ++k) { size_t i = base + k * 256 + tid; Whhb[i] = f2bf(Whh[i]); }
        } else if (pb < 532) {
            size_t base = (size_t)(pb - 528) * 16384;
#pragma unroll
            for (int k = 0; k < 64; ++k) { size_t i = base + k * 256 + tid; Whob[i] = f2bf(Who[i]); }
        } else {
            size_t base = (size_t)(pb - 532) * 4096;
#pragma unroll
            for (int k = 0; k < 16; ++k) { size_t i = base + k * 256 + tid; xbf[i] = f2bf(x[i]); }
        }
        return;
    }

    // ---------------- recurrence: block g owns samples [g*16, g*16+16) ------
    char* bufs = smem;                          // 2 x 10240 B
    const int g = bid;
    const int lane = tid & 63, w = tid >> 6;
    const int l15 = lane & 15, quad = lane >> 4;
    const int bq = tid >> 4, o4 = tid & 15;     // x-staging role

    // A-fragments: Wcc (kb 0..7) + Wic (kb 8..9); row j = w*64+mt*16+l15
    short8 wf[4][8], wi[4][2];
#pragma unroll
    for (int mt = 0; mt < 4; ++mt) {
        const int j = w * 64 + mt * 16 + l15;
#pragma unroll
        for (int kb = 0; kb < 8; ++kb) {
            const float* src = Wcc + (size_t)j * 256 + kb * 32 + quad * 8;
            float4 a = *(const float4*)src;
            float4 b = *(const float4*)(src + 4);
            short8 s;
            s[0] = (short)f2bf(a.x); s[1] = (short)f2bf(a.y);
            s[2] = (short)f2bf(a.z); s[3] = (short)f2bf(a.w);
            s[4] = (short)f2bf(b.x); s[5] = (short)f2bf(b.y);
            s[6] = (short)f2bf(b.z); s[7] = (short)f2bf(b.w);
            wf[mt][kb] = s;
        }
#pragma unroll
        for (int kb = 0; kb < 2; ++kb) {
            const float* src = Wic + (size_t)j * 64 + kb * 32 + quad * 8;
            float4 a = *(const float4*)src;
            float4 b = *(const float4*)(src + 4);
            short8 s;
            s[0] = (short)f2bf(a.x); s[1] = (short)f2bf(a.y);
            s[2] = (short)f2bf(a.z); s[3] = (short)f2bf(a.w);
            s[4] = (short)f2bf(b.x); s[5] = (short)f2bf(b.y);
            s[6] = (short)f2bf(b.z); s[7] = (short)f2bf(b.w);
            wi[mt][kb] = s;
        }
    }
    float4 bias[4];
#pragma unroll
    for (int mt = 0; mt < 4; ++mt) {
        const int j0 = w * 64 + mt * 16 + quad * 4;
        float4 b1 = *(const float4*)(bic + j0);
        float4 b2 = *(const float4*)(bcc + j0);
        bias[mt] = (float4){b1.x + b2.x, b1.y + b2.y, b1.z + b2.z, b1.w + b2.w};
    }
    // init buf0: ctx=0 (granule rows 0..31), x_0 (rows 32..39)
    *(uint4*)(bufs + tid * 16) = (uint4){0, 0, 0, 0};
    *(uint4*)(bufs + (tid + 256) * 16) = (uint4){0, 0, 0, 0};
    {
        float4 xv = *(const float4*)(x + (size_t)(g * 16 + bq) * 64 + o4 * 4);
        short4v s4;
        s4[0] = (short)f2bf(xv.x); s4[1] = (short)f2bf(xv.y);
        s4[2] = (short)f2bf(xv.z); s4[3] = (short)f2bf(xv.w);
        *(short4v*)(bufs + (32 + (o4 >> 1)) * 256 + bq * 16 + (o4 & 1) * 8) = s4;
    }
    float4 y[4];
#pragma unroll
    for (int mt = 0; mt < 4; ++mt) y[mt] = (float4){0.f, 0.f, 0.f, 0.f};
    __syncthreads();

    int p = 0;
#pragma unroll 1
    for (int t = 0; t < 256; ++t) {
        char* bp = bufs + p * 10240;
        char* bn = bufs + (p ^ 1) * 10240;
        // CTXT2[c>>1][m][c&1] = ctx entering step t (= y); m = t*128+g*16+l15
#pragma unroll
        for (int mt = 0; mt < 4; ++mt) {
            const int j0 = w * 64 + mt * 16 + quad * 4;     // multiple of 4
            const size_t mi = (size_t)(t * 128 + g * 16 + l15) * 2;
            const size_t pr = (size_t)(j0 >> 1) * 65536 + mi;
            *(float2*)(CTXT + pr)         = (float2){y[mt].x, y[mt].y};
            *(float2*)(CTXT + pr + 65536) = (float2){y[mt].z, y[mt].w};
        }
        float4 xv;
        if (t < 255)
            xv = *(const float4*)(x + (size_t)((t + 1) * 128 + g * 16 + bq) * 64 + o4 * 4);
        floatx4 acc[4];
#pragma unroll
        for (int mt = 0; mt < 4; ++mt) acc[mt] = (floatx4){0.f, 0.f, 0.f, 0.f};
#pragma unroll
        for (int kb = 0; kb < 8; ++kb) {
            short8 bf = *(const short8*)(bp + (kb * 4 + quad) * 256 + l15 * 16);
#pragma unroll
            for (int mt = 0; mt < 4; ++mt)
                acc[mt] = __builtin_amdgcn_mfma_f32_16x16x32_bf16(wf[mt][kb], bf, acc[mt], 0, 0, 0);
        }
#pragma unroll
        for (int kb = 0; kb < 2; ++kb) {
            short8 bf = *(const short8*)(bp + ((8 + kb) * 4 + quad) * 256 + l15 * 16);
#pragma unroll
            for (int mt = 0; mt < 4; ++mt)
                acc[mt] = __builtin_amdgcn_mfma_f32_16x16x32_bf16(wi[mt][kb], bf, acc[mt], 0, 0, 0);
        }
#pragma unroll
        for (int mt = 0; mt < 4; ++mt) {
            y[mt].x = fmaxf(acc[mt][0] + bias[mt].x, 0.f);
            y[mt].y = fmaxf(acc[mt][1] + bias[mt].y, 0.f);
            y[mt].z = fmaxf(acc[mt][2] + bias[mt].z, 0.f);
            y[mt].w = fmaxf(acc[mt][3] + bias[mt].w, 0.f);
        }
        if (t < 255) {
#pragma unroll
            for (int mt = 0; mt < 4; ++mt) {
                const int c0 = w * 64 + mt * 16 + quad * 4;
                short4v s4;
                s4[0] = (short)f2bf(y[mt].x); s4[1] = (short)f2bf(y[mt].y);
                s4[2] = (short)f2bf(y[mt].z); s4[3] = (short)f2bf(y[mt].w);
                *(short4v*)(bn + (c0 >> 3) * 256 + l15 * 16 + (c0 & 7) * 2) = s4;
            }
            short4v s4;
            s4[0] = (short)f2bf(xv.x); s4[1] = (short)f2bf(xv.y);
            s4[2] = (short)f2bf(xv.z); s4[3] = (short)f2bf(xv.w);
            *(short4v*)(bn + (32 + (o4 >> 1)) * 256 + bq * 16 + (o4 & 1) * 8) = s4;
        }
        __syncthreads();
        p ^= 1;
    }
#pragma unroll
    for (int mt = 0; mt < 4; ++mt) {
        const int j0 = w * 64 + mt * 16 + quad * 4;
#pragma unroll
        for (int r = 0; r < 4; ++r)
            ctx_out[(size_t)(g * 16 + l15) * 256 + j0 + r] = (&y[mt].x)[r];
    }
}

// ---------------------------------------------------------------------------
// BIG GEMM: M=32768,N=512,K=16448, scale folded into A-fragments.
// 256 thr / 4 waves, block tile 256x128, wave tile 64m x 128n (mt=4: each
// LDS B-fragment feeds 4 MFMAs). BK=128, LDS double-buffer (2x32 KB),
// glds(16B) prefetch after the single per-iter barrier. Grid 512, XCD
// swizzle by = gidx&3.
// Register budget (R4 lesson): acc=128 AGPR -> arch cap = 256-128 = 128.
// Arch diet: gq[4]+QSH const (q,q+4 granules share XOR phase, +16 B-rows);
// scales via one float2 pointer + mt*128B immediate offsets (CTXT2 layout).
// ---------------------------------------------------------------------------
__global__ __launch_bounds__(256, 2) void k_big(const ushort_t* __restrict__ xbf,
                                                const ushort_t* __restrict__ WbT,
                                                const float* __restrict__ CTXT,
                                                ushort_t* __restrict__ hbf) {
    __shared__ __align__(16) ushort_t Bt[2 * 128 * 128];   // 64 KB
    const int tid = threadIdx.x;
    const int lane = tid & 63, w = tid >> 6;               // 4 waves
    const int l15 = lane & 15, quad = lane >> 4;
    const int gidx = blockIdx.x;
    const int by = gidx & 3;                               // xcd = gidx&7
    const int bx = (gidx >> 3) * 2 + ((gidx >> 2) & 1);    // 0..127
    const int m0 = bx * 256, n0 = by * 128;
    const int mrb = m0 + w * 64 + l15;                     // mt=0 A-row

    short8 afr[4][2];                                      // [mt][ks]: x row frag
#pragma unroll
    for (int mt = 0; mt < 4; ++mt) {
        afr[mt][0] = *(const short8*)(xbf + (size_t)(mrb + mt * 16) * 64 + quad * 8);
        afr[mt][1] = *(const short8*)(xbf + (size_t)(mrb + mt * 16) * 64 + 32 + quad * 8);
    }

    floatx4 acc[4][8];
#pragma unroll
    for (int mt = 0; mt < 4; ++mt)
#pragma unroll
        for (int nt = 0; nt < 8; ++nt) acc[mt][nt] = (floatx4){0.f, 0.f, 0.f, 0.f};

    // staging: granule G = w*512 + q*64 + lane, q in 0..7; q+4 has the same
    // XOR phase as q ((G+256)&15==G&15, (nr+16)&15==nr&15) at +16 B-rows.
    const ushort_t* gq[4];
#pragma unroll
    for (int q = 0; q < 4; ++q) {
        const int G = w * 512 + q * 64 + lane;
        const int nr = G >> 4;
        const int k8 = (G & 15) ^ (nr & 15);
        gq[q] = WbT + (size_t)(n0 + nr) * 16448 + k8 * 8;
    }
    const size_t QSH = (size_t)16 * 16448;                 // +16 rows (ushorts)
    ushort_t* lqb = Bt + w * 4096;                         // wave-uniform base
#pragma unroll
    for (int q = 0; q < 4; ++q) {                          // tile 0 -> buf 0
        glds16(gq[q], lqb + q * 512);
        glds16(gq[q] + QSH, lqb + q * 512 + 2048);
    }

    // scales: pair-row kk holds (c=2kk, c=2kk+1) as float2 at [m]
    const float* cp = CTXT + (size_t)mrb * 2;              // pair-row 0, this lane
    float2 sc[4];
#pragma unroll
    for (int mt = 0; mt < 4; ++mt) sc[mt] = *(const float2*)(cp + mt * 32);

    for (int kk = 0; kk < 129; ++kk) {
        const int p = kk & 1;
        __syncthreads();                                   // tile kk resident
        if (kk < 128) {                                    // prefetch tile kk+1
            const size_t koff = (size_t)(kk + 1) * 128;
            ushort_t* ln_ = Bt + (p ^ 1) * 16384 + w * 4096;
#pragma unroll
            for (int q = 0; q < 4; ++q) {
                glds16(gq[q] + koff, ln_ + q * 512);
                glds16(gq[q] + koff + QSH, ln_ + q * 512 + 2048);
            }
        }
        float2 scn[4];
        if (kk + 1 < 128) {
            const float* cpn = cp + (size_t)(kk + 1) * 65536;
#pragma unroll
            for (int mt = 0; mt < 4; ++mt) scn[mt] = *(const float2*)(cpn + mt * 32);
        } else {
#pragma unroll
            for (int mt = 0; mt < 4; ++mt) scn[mt] = (float2){1.f, 1.f};
        }
        const ushort_t* bb = Bt + p * 16384;
        if (kk < 128) {
#pragma unroll
            for (int h = 0; h < 2; ++h) {
#pragma unroll
                for (int ks = 0; ks < 2; ++ks) {
                    short8 a0 = scale8(afr[0][ks], h ? sc[0].y : sc[0].x);
                    short8 a1 = scale8(afr[1][ks], h ? sc[1].y : sc[1].x);
                    short8 a2 = scale8(afr[2][ks], h ? sc[2].y : sc[2].x);
                    short8 a3 = scale8(afr[3][ks], h ? sc[3].y : sc[3].x);
#pragma unroll
                    for (int nt = 0; nt < 8; ++nt) {
                        const int nr2 = nt * 16 + l15;
                        const char* bpr = (const char*)bb + nr2 * 256;
                        short8 b = *(const short8*)(bpr + (((h * 8 + ks * 4 + quad) ^ l15) * 16));
                        acc[0][nt] = __builtin_amdgcn_mfma_f32_16x16x32_bf16(a0, b, acc[0][nt], 0, 0, 0);
                        acc[1][nt] = __builtin_amdgcn_mfma_f32_16x16x32_bf16(a1, b, acc[1][nt], 0, 0, 0);
                        acc[2][nt] = __builtin_amdgcn_mfma_f32_16x16x32_bf16(a2, b, acc[2][nt], 0, 0, 0);
                        acc[3][nt] = __builtin_amdgcn_mfma_f32_16x16x32_bf16(a3, b, acc[3][nt], 0, 0, 0);
                    }
                }
            }
        } else {                                           // bias block, scale=1
#pragma unroll
            for (int ks = 0; ks < 2; ++ks) {
#pragma unroll
                for (int nt = 0; nt < 8; ++nt) {
                    const int nr2 = nt * 16 + l15;
                    const char* bpr = (const char*)bb + nr2 * 256;
                    short8 b = *(const short8*)(bpr + (((ks * 4 + quad) ^ l15) * 16));
#pragma unroll
                    for (int mt = 0; mt < 4; ++mt)
                        acc[mt][nt] = __builtin_amdgcn_mfma_f32_16x16x32_bf16(afr[mt][ks], b, acc[mt][nt], 0, 0, 0);
                }
            }
        }
#pragma unroll
        for (int mt = 0; mt < 4; ++mt) sc[mt] = scn[mt];
    }
    // epilogue: C/D col = n0+nt*16+l15, row = m0 + w*64 + mt*16 + quad*4 + r
#pragma unroll
    for (int mt = 0; mt < 4; ++mt)
#pragma unroll
        for (int nt = 0; nt < 8; ++nt) {
            const int col = n0 + nt * 16 + l15;
#pragma unroll
            for (int r = 0; r < 4; ++r) {
                const int row = m0 + w * 64 + mt * 16 + quad * 4 + r;
                hbf[(size_t)row * 512 + col] = f2bf(fmaxf(acc[mt][nt][r], 0.f));
            }
        }
}

// ---------------------------------------------------------------------------
// Generic bf16 NT GEMM: C[m,n] = sum_k A[m,k]*B[n,k] + bias[n]
// ---------------------------------------------------------------------------
template <bool OUTF32>
__global__ __launch_bounds__(256, 2) void k_gemm_nt(const ushort_t* __restrict__ A,
                                                    const ushort_t* __restrict__ Bm,
                                                    const float* __restrict__ bias,
                                                    ushort_t* __restrict__ outb,
                                                    float* __restrict__ outf,
                                                    int K, int Nst) {
    __shared__ __align__(16) ushort_t At[128 * 72];
    __shared__ __align__(16) ushort_t Bt[128 * 72];
    const int tid = threadIdx.x;
    const int lane = tid & 63, w = tid >> 6;
    const int wm = w & 1, wn = w >> 1;
    const int l15 = lane & 15, quad = lane >> 4;
    const int m0 = blockIdx.x * 128, n0 = blockIdx.y * 128;

    const int r_l = tid >> 1, kh = (tid & 1) * 32;
    const ushort_t* gA = A + (size_t)(m0 + r_l) * K + kh;
    const ushort_t* gB = Bm + (size_t)(n0 + r_l) * K + kh;
    ushort_t* lA = &At[r_l * 72 + kh];
    ushort_t* lB = &Bt[r_l * 72 + kh];

    uint4 ra0 = *(const uint4*)(gA + 0), ra1 = *(const uint4*)(gA + 8);
    uint4 ra2 = *(const uint4*)(gA + 16), ra3 = *(const uint4*)(gA + 24);
    uint4 rb0 = *(const uint4*)(gB + 0), rb1 = *(const uint4*)(gB + 8);
    uint4 rb2 = *(const uint4*)(gB + 16), rb3 = *(const uint4*)(gB + 24);

    floatx4 acc[4][4];
#pragma unroll
    for (int i = 0; i < 4; ++i)
#pragma unroll
        for (int j = 0; j < 4; ++j) acc[i][j] = (floatx4){0.f, 0.f, 0.f, 0.f};

    const int niter = K >> 6;
    for (int kb = 0; kb < niter; ++kb) {
        __syncthreads();
        *(uint4*)(lA + 0) = ra0;  *(uint4*)(lA + 8) = ra1;
        *(uint4*)(lA + 16) = ra2; *(uint4*)(lA + 24) = ra3;
        *(uint4*)(lB + 0) = rb0;  *(uint4*)(lB + 8) = rb1;
        *(uint4*)(lB + 16) = rb2; *(uint4*)(lB + 24) = rb3;
        __syncthreads();
        if (kb + 1 < niter) {
            const ushort_t* ga = gA + (size_t)(kb + 1) * 64;
            const ushort_t* gb = gB + (size_t)(kb + 1) * 64;
            ra0 = *(const uint4*)(ga + 0);  ra1 = *(const uint4*)(ga + 8);
            ra2 = *(const uint4*)(ga + 16); ra3 = *(const uint4*)(ga + 24);
            rb0 = *(const uint4*)(gb + 0);  rb1 = *(const uint4*)(gb + 8);
            rb2 = *(const uint4*)(gb + 16); rb3 = *(const uint4*)(gb + 24);
        }
        short8 av[4][2];
#pragma unroll
        for (int mt = 0; mt < 4; ++mt) {
            const int mr2 = wm * 64 + mt * 16 + l15;
            av[mt][0] = *(const short8*)(&At[mr2 * 72 + quad * 8]);
            av[mt][1] = *(const short8*)(&At[mr2 * 72 + 32 + quad * 8]);
        }
#pragma unroll
        for (int nt = 0; nt < 4; ++nt) {
            const int nr = wn * 64 + nt * 16 + l15;
            short8 b0 = *(const short8*)(&Bt[nr * 72 + quad * 8]);
            short8 b1 = *(const short8*)(&Bt[nr * 72 + 32 + quad * 8]);
#pragma unroll
            for (int mt = 0; mt < 4; ++mt) {
                acc[mt][nt] = __builtin_amdgcn_mfma_f32_16x16x32_bf16(av[mt][0], b0, acc[mt][nt], 0, 0, 0);
                acc[mt][nt] = __builtin_amdgcn_mfma_f32_16x16x32_bf16(av[mt][1], b1, acc[mt][nt], 0, 0, 0);
            }
        }
    }
#pragma unroll
    for (int mt = 0; mt < 4; ++mt)
#pragma unroll
        for (int nt = 0; nt < 4; ++nt) {
            const int col = n0 + wn * 64 + nt * 16 + l15;
            const float bb = bias[col];
#pragma unroll
            for (int r = 0; r < 4; ++r) {
                const int row = m0 + wm * 64 + mt * 16 + quad * 4 + r;
                const float v = acc[mt][nt][r] + bb;
                if (OUTF32) outf[(size_t)row * Nst + col] = v;
                else        outb[(size_t)row * Nst + col] = f2bf(v);
            }
        }
}

// ---------------------------------------------------------------------------
// LayerNorm + residual: z = h + relu( LN(hn)*g + b ), in-place over hbf.
// ---------------------------------------------------------------------------
__global__ __launch_bounds__(256, 1) void k_ln(const ushort_t* __restrict__ hn,
                                               ushort_t* __restrict__ h,
                                               const float* __restrict__ g,
                                               const float* __restrict__ bb) {
    const int tid = threadIdx.x;
    const int lane = tid & 63;
    const int row = blockIdx.x * 4 + (tid >> 6);
    const uint4 hv = *(const uint4*)(hn + (size_t)row * 512 + lane * 8);
    float f[8];
    f[0] = blo(hv.x); f[1] = bhi(hv.x); f[2] = blo(hv.y); f[3] = bhi(hv.y);
    f[4] = blo(hv.z); f[5] = bhi(hv.z); f[6] = blo(hv.w); f[7] = bhi(hv.w);
    float s = 0.f, s2 = 0.f;
#pragma unroll
    for (int j = 0; j < 8; ++j) { s += f[j]; s2 = fmaf(f[j], f[j], s2); }
#pragma unroll
    for (int o = 32; o >= 1; o >>= 1) { s += __shfl_xor(s, o, 64); s2 += __shfl_xor(s2, o, 64); }
    const float mu = s * (1.f / 512.f);
    const float var = s2 * (1.f / 512.f) - mu * mu;
    const float rs = rsqrtf(var + 1e-5f);
    const uint4 hh = *(const uint4*)(h + (size_t)row * 512 + lane * 8);
    float hf[8];
    hf[0] = blo(hh.x); hf[1] = bhi(hh.x); hf[2] = blo(hh.y); hf[3] = bhi(hh.y);
    hf[4] = blo(hh.z); hf[5] = bhi(hh.z); hf[6] = blo(hh.w); hf[7] = bhi(hh.w);
    float4 g0 = *(const float4*)(g + lane * 8);  float4 g1 = *(const float4*)(g + lane * 8 + 4);
    float4 b0 = *(const float4*)(bb + lane * 8); float4 b1 = *(const float4*)(bb + lane * 8 + 4);
    const float gv[8] = {g0.x, g0.y, g0.z, g0.w, g1.x, g1.y, g1.z, g1.w};
    const float bv[8] = {b0.x, b0.y, b0.z, b0.w, b1.x, b1.y, b1.z, b1.w};
    float z[8];
#pragma unroll
    for (int j = 0; j < 8; ++j)
        z[j] = hf[j] + fmaxf((f[j] - mu) * rs * gv[j] + bv[j], 0.f);
    uint4 o;
    o.x = pack2(z[0], z[1]); o.y = pack2(z[2], z[3]);
    o.z = pack2(z[4], z[5]); o.w = pack2(z[6], z[7]);
    *(uint4*)(h + (size_t)row * 512 + lane * 8) = o;
}

// ---------------------------------------------------------------------------
extern "C" void kernel_launch(void* const* d_in, const int* in_sizes, int n_in,
                              void* d_out, int out_size, void* d_ws, size_t ws_size,
                              hipStream_t stream) {
    const float* x    = (const float*)d_in[0];
    const float* Wcc  = (const float*)d_in[1];
    const float* bcc  = (const float*)d_in[2];
    const float* Wic  = (const float*)d_in[3];
    const float* bic  = (const float*)d_in[4];
    const float* Wmap = (const float*)d_in[5];
    const float* bmap = (const float*)d_in[6];
    const float* Whh  = (const float*)d_in[7];
    const float* bhh  = (const float*)d_in[8];
    const float* ln_g = (const float*)d_in[9];
    const float* ln_b = (const float*)d_in[10];
    const float* Who  = (const float*)d_in[11];
    const float* bho  = (const float*)d_in[12];
    float* out = (float*)d_out;

    char* wsb = (char*)d_ws;
    ushort_t* WbT  = (ushort_t*)(wsb);                    // 16,842,752 B + 1 KB pad
    ushort_t* Whhb = (ushort_t*)(wsb + 16843776);         //    524,288
    ushort_t* Whob = (ushort_t*)(wsb + 17368064);         //    131,072
    ushort_t* xbf  = (ushort_t*)(wsb + 17499136);         //  4,194,304
    float*    CTXT = (float*)   (wsb + 21693440);         // 33,554,432 (pair layout)
    ushort_t* hbf  = (ushort_t*)(wsb + 55247872);         // 33,554,432 (h, then z)
    ushort_t* hnbf = (ushort_t*)(wsb + 88802304);         // 33,554,432 -> ~122 MB

    k_fused<<<1052, 256, 0, stream>>>(x, Wcc, bcc, Wic, bic, Wmap, bmap, Whh, Who,
                                      WbT, Whhb, Whob, xbf, CTXT, out + 4194304);
    k_big<<<512, 256, 0, stream>>>(xbf, WbT, CTXT, hbf);
    k_gemm_nt<false><<<dim3(256, 4), 256, 0, stream>>>(hbf, Whhb, bhh, hnbf, nullptr, 512, 512);
    k_ln<<<8192, 256, 0, stream>>>(hnbf, hbf, ln_g, ln_b);
    k_gemm_nt<true><<<dim3(256, 1), 256, 0, stream>>>(hbf, Whob, bho, nullptr, out, 512, 128);
}